// Round 1
// baseline (423.509 us; speedup 1.0000x reference)
//
#include <hip/hip_runtime.h>
#include <hip/hip_bf16.h>
#include <math.h>

#define NN 100000      // nodes
#define NE 1600000     // edges
#define NF 256         // input features
#define NH 128         // hidden
#define NC 40          // classes
#define NCP 64         // padded classes for W2t (rows >=40 zero)
#define NC2 48         // packed H2p row width (classes 40..47 are zero)

// Workspace layout (4-byte units):
//   counts     [0,       100032)
//   offsets    [100032,  200128)   (NN+1 used)
//   bin_cursor [200128,  300160)   (NBINS used)
//   dinv       [300160,  400192)
//   erec       [400192,  3600192)  (NE int2)
//   H          [3600192, 10000192) (bf16 NN*NH; scan scratch early; packed H2p after agg1)
//   w1t        [10000192,10016576) (bf16 [128][256])
//   w2t        [10016576,10020672) (bf16 [64][128], rows >=40 zero)
//   Hagg       [16400192,29200192) (bf16 NN*NH after agg1; ebin [NE ints] lives here first)
#define OFF_OFFSETS 100032
#define OFF_CURSOR  200128
#define OFF_DINV    300160
#define OFF_EREC    400192
#define OFF_H       3600192
#define OFF_W1T     10000192
#define OFF_W2T     10016576
#define OFF_HAGG    16400192

#define SCAN_TILE 1024
#define SCAN_NB   ((NN + SCAN_TILE - 1) / SCAN_TILE)   // 98

#define GEMM1_NB  ((NN + 127) / 128)    // 782
#define NBINS     ((NN + 255) / 256)    // 391
#define CHUNK_A   4096
#define NB_A      ((NE + CHUNK_A - 1) / CHUNK_A)       // 391 (= GEMM1_NB/2)

using f32x4  = __attribute__((ext_vector_type(4))) float;
using bf16x8 = __attribute__((ext_vector_type(8))) short;

// decode packed pair of bf16 (lo, hi) to fp32x2 — exact, pure bit ops
__device__ inline float2 cvt2(unsigned u) {
    float2 f;
    f.x = __uint_as_float(u << 16);
    f.y = __uint_as_float(u & 0xffff0000u);
    return f;
}

__device__ inline short bfbits(float f) {
    __hip_bfloat16 h = __float2bfloat16(f);
    return *reinterpret_cast<short*>(&h);
}

__device__ inline unsigned pk2(float lo, float hi) {
    return (unsigned)(unsigned short)bfbits(lo) | ((unsigned)(unsigned short)bfbits(hi) << 16);
}

// ---------------- count + W1t/W2t prep (fused, independent work) ----------------
__global__ void count_prep(const int* __restrict__ dst, int* __restrict__ count,
                           const float* __restrict__ W1, __hip_bfloat16* __restrict__ W1t,
                           const float* __restrict__ W2, __hip_bfloat16* __restrict__ W2t) {
    int t = blockIdx.x * blockDim.x + threadIdx.x;
    if (t < NE) atomicAdd(&count[dst[t]], 1);
    if (t < NH * NF) {
        int n = t >> 8;
        int k = t & (NF - 1);
        W1t[t] = __float2bfloat16(W1[(size_t)k * NH + n]);
    }
    if (t < NCP * NH) {
        int n = t >> 7;
        int k = t & (NH - 1);
        W2t[t] = __float2bfloat16((n < NC) ? W2[(size_t)k * NC + n] : 0.f);
    }
}

// ---- hierarchical scan (phase2 fused into phase3) ----
__global__ void scan_phase1(const int* __restrict__ count, int* __restrict__ blocksums) {
    int b = blockIdx.x, t = threadIdx.x;
    int i = b * SCAN_TILE + t;
    int v = (i < NN) ? count[i] : 0;
    #pragma unroll
    for (int off = 32; off; off >>= 1) v += __shfl_xor(v, off, 64);
    __shared__ int ws[16];
    int lane = t & 63, wave = t >> 6;
    if (lane == 0) ws[wave] = v;
    __syncthreads();
    if (t == 0) {
        int s = 0;
        #pragma unroll
        for (int w = 0; w < SCAN_TILE / 64; ++w) s += ws[w];
        blocksums[b] = s;
    }
}

// phase 3: block prefix (from blocksums) + offsets + dinv + per-bin cursor bases
__global__ void scan_phase3(const int* __restrict__ count, const int* __restrict__ blocksums,
                            int* __restrict__ offsets, int* __restrict__ bin_cursor,
                            float* __restrict__ dinv) {
    int b = blockIdx.x, t = threadIdx.x;
    int lane = t & 63, wave = t >> 6;

    // fused phase2: sum blocksums[0..b-1] using first 2 waves (SCAN_NB=98 <= 128)
    __shared__ int bsum2[2];
    if (t < 128) {
        int u = (t < b) ? blocksums[t] : 0;   // t < b <= 97 < SCAN_NB, in bounds
        #pragma unroll
        for (int off = 32; off; off >>= 1) u += __shfl_xor(u, off, 64);
        if (lane == 0) bsum2[wave] = u;
    }

    int i = b * SCAN_TILE + t;
    int v = (i < NN) ? count[i] : 0;
    int s = v;
    #pragma unroll
    for (int off = 1; off < 64; off <<= 1) {
        int u = __shfl_up(s, off, 64);
        if (lane >= off) s += u;
    }
    __shared__ int wsum[16];
    if (lane == 63) wsum[wave] = s;
    __syncthreads();
    if (t < 16) {
        int x = wsum[t];
        #pragma unroll
        for (int off = 1; off < 16; off <<= 1) {
            int u = __shfl_up(x, off, 64);
            if (t >= off) x += u;
        }
        wsum[t] = x;
    }
    __syncthreads();
    int bpref = bsum2[0] + bsum2[1];
    int excl = (s - v) + (wave ? wsum[wave - 1] : 0) + bpref;
    if (i < NN) {
        offsets[i] = excl;
        dinv[i]    = rsqrtf((float)v + 1.0f);   // +1 self loop
        if ((i & 255) == 0) bin_cursor[i >> 8] = excl;
        if (i == NN - 1) offsets[NN] = excl + v;
    }
}

// ---------------- FUSED + INTERLEAVED: layer-1 MFMA GEMM (double-buffered) + pass A ----------------
// Block pattern (3k blocks): b%3==1 -> passA chunk b/3; else gemm tile 2*(b/3)+(b%3==2)
__global__ __launch_bounds__(256, 3) void gemm1_passA(
        const int* __restrict__ ei, int* __restrict__ bin_cursor,
        int* __restrict__ ebin,
        const float* __restrict__ X, const __hip_bfloat16* __restrict__ W1t,
        __hip_bfloat16* __restrict__ H) {
    __shared__ __align__(16) int smem[12288];   // 48 KB: gemm As dbuf(32K)+Bs dbuf(16K) OR passA hist/rbase

    const int bi = blockIdx.x / 3;
    const int br = blockIdx.x % 3;

    if (br == 1) {
        // ---- pass A: partition 4096 edges into 256-node bins, run-coalesced writes ----
        int* hist  = smem;
        int* rbase = smem + NBINS;
        int e0 = bi * CHUNK_A;
        int e1 = e0 + CHUNK_A; if (e1 > NE) e1 = NE;
        for (int j = threadIdx.x; j < NBINS; j += 256) hist[j] = 0;
        __syncthreads();
        for (int p = e0 + threadIdx.x; p < e1; p += 256)
            atomicAdd(&hist[ei[NE + p] >> 8], 1);
        __syncthreads();
        for (int j = threadIdx.x; j < NBINS; j += 256) {
            int c = hist[j];
            rbase[j] = c ? atomicAdd(&bin_cursor[j], c) : 0;
        }
        __syncthreads();
        for (int p = e0 + threadIdx.x; p < e1; p += 256) {
            int s = ei[p];
            int d = ei[NE + p];
            int bb = d >> 8;
            int pos = atomicAdd(&rbase[bb], 1);
            ebin[pos] = s | ((d & 255) << 17);
        }
        return;
    }

    // ---- gemm1 path: H = bf16(x @ W1), 128x128 tile, 2-phase double-buffered K-loop ----
    float* As = (float*)smem;           // 2 x [128][32] fp32 (buf stride 4096 floats)
    short* Bs = (short*)(smem + 8192);  // 2 x [128][32] bf16 (buf stride 4096 shorts)

    const int tid  = threadIdx.x;
    const int wave = tid >> 6;
    const int lane = tid & 63;
    const int quad = lane >> 4;
    const int l16  = lane & 15;
    const int wy = wave >> 1, wx = wave & 1;
    const int m0 = (bi * 2 + (br == 2 ? 1 : 0)) * 128;

    f32x4 acc[4][4] = {};

    auto stage = [&](int d, int kk) {
        #pragma unroll
        for (int i = 0; i < 4; ++i) {
            int c   = i * 256 + tid;
            int row = c >> 3, cc = c & 7;
            int gr  = m0 + row; if (gr > NN - 1) gr = NN - 1;
            const float* gp = X + (size_t)gr * NF + kk + cc * 4;
            __builtin_amdgcn_global_load_lds(
                (const __attribute__((address_space(1))) void*)gp,
                (__attribute__((address_space(3))) void*)&As[d * 4096 + (i * 256 + wave * 64) * 4],
                16, 0, 0);
        }
        #pragma unroll
        for (int i = 0; i < 2; ++i) {
            int c = i * 256 + tid;
            int n = c >> 2, cc = c & 3;
            const __hip_bfloat16* gp = W1t + (size_t)n * NF + kk + cc * 8;
            __builtin_amdgcn_global_load_lds(
                (const __attribute__((address_space(1))) void*)gp,
                (__attribute__((address_space(3))) void*)&Bs[d * 4096 + (i * 256 + wave * 64) * 8],
                16, 0, 0);
        }
    };

    // prologue: fill buffer 0, drain, barrier
    stage(0, 0);
    __syncthreads();

    int cur = 0;
    #pragma unroll
    for (int k0 = 0; k0 < NF; k0 += 32) {
        if (k0 + 32 < NF) stage(cur ^ 1, k0 + 32);   // prefetch next tile (in flight during MFMA)

        bf16x8 a_frag[4], b_frag[4];
        #pragma unroll
        for (int mi = 0; mi < 4; ++mi) {
            const float* ap = &As[cur * 4096 + (wy * 64 + mi * 16 + l16) * 32 + quad * 8];
            f32x4 a0 = *(const f32x4*)ap;
            f32x4 a1 = *(const f32x4*)(ap + 4);
            bf16x8 af;
            af[0] = bfbits(a0.x); af[1] = bfbits(a0.y);
            af[2] = bfbits(a0.z); af[3] = bfbits(a0.w);
            af[4] = bfbits(a1.x); af[5] = bfbits(a1.y);
            af[6] = bfbits(a1.z); af[7] = bfbits(a1.w);
            a_frag[mi] = af;
        }
        #pragma unroll
        for (int ni = 0; ni < 4; ++ni) {
            const short* bp = &Bs[cur * 4096 + (wx * 64 + ni * 16 + l16) * 32 + quad * 8];
            b_frag[ni] = *(const bf16x8*)bp;
        }
        #pragma unroll
        for (int mi = 0; mi < 4; ++mi)
            #pragma unroll
            for (int ni = 0; ni < 4; ++ni)
                acc[mi][ni] = __builtin_amdgcn_mfma_f32_16x16x32_bf16(
                    a_frag[mi], b_frag[ni], acc[mi][ni], 0, 0, 0);

        __syncthreads();   // drains this iter's prefetch (vmcnt 0) + protects buffer swap
        cur ^= 1;
    }

    #pragma unroll
    for (int mi = 0; mi < 4; ++mi)
        #pragma unroll
        for (int v = 0; v < 4; ++v) {
            int r = m0 + wy * 64 + mi * 16 + quad * 4 + v;
            if (r < NN) {
                #pragma unroll
                for (int ni = 0; ni < 4; ++ni) {
                    int c = wx * 64 + ni * 16 + l16;
                    H[(size_t)r * NH + c] = __float2bfloat16(acc[mi][ni][v]);
                }
            }
        }
}

// ---------------- pass B: within-bin counting sort -> erec (L2-local writes) ----------------
__global__ __launch_bounds__(256) void passB(const int* __restrict__ offsets,
                                             const int* __restrict__ ebin,
                                             const float* __restrict__ dinv,
                                             int2* __restrict__ erec) {
    int b = blockIdx.x;
    int n0 = b << 8;
    int nodes = NN - n0; if (nodes > 256) nodes = 256;
    __shared__ int cur[256];
    __shared__ float dls[256];
    if (threadIdx.x < nodes) {
        cur[threadIdx.x] = offsets[n0 + threadIdx.x];
        dls[threadIdx.x] = dinv[n0 + threadIdx.x];
    }
    __syncthreads();
    int binstart = offsets[n0];
    int binend   = offsets[n0 + nodes];
    for (int p = binstart + threadIdx.x; p < binend; p += 256) {
        int e  = ebin[p];
        int s  = e & 0x1FFFF;
        int dl = e >> 17;
        int pos = atomicAdd(&cur[dl], 1);
        float w = dinv[s] * dls[dl];
        erec[pos] = make_int2(s, __float_as_int(w));
    }
}

// ---------------- layer-2 GEMM via MFMA (double-buffered): H2p = bf16(Haggb @ W2[:,0:48]) ----------------
// H2p rows packed to NC2=48 bf16 (classes 40..47 are zeros from W2t padding)
__global__ __launch_bounds__(256) void gemm2_mfma(const __hip_bfloat16* __restrict__ Haggb,
                                                  const __hip_bfloat16* __restrict__ W2t,
                                                  __hip_bfloat16* __restrict__ H2p) {
    __shared__ __align__(16) short As2[2][128 * 32];  // 2 x 8 KB
    __shared__ __align__(16) short Bs2[2][64 * 32];   // 2 x 4 KB
    const int tid  = threadIdx.x;
    const int wave = tid >> 6;
    const int lane = tid & 63;
    const int quad = lane >> 4;
    const int l16  = lane & 15;
    const int m0 = blockIdx.x * 128;

    f32x4 acc[2][3] = {};

    auto stage = [&](int d, int kk) {
        #pragma unroll
        for (int i = 0; i < 2; ++i) {
            int c = i * 256 + tid;
            int row = c >> 2, cc = c & 3;
            int gr = m0 + row; if (gr > NN - 1) gr = NN - 1;
            const __hip_bfloat16* gp = Haggb + (size_t)gr * NH + kk + cc * 8;
            __builtin_amdgcn_global_load_lds(
                (const __attribute__((address_space(1))) void*)gp,
                (__attribute__((address_space(3))) void*)&As2[d][(i * 256 + wave * 64) * 8],
                16, 0, 0);
        }
        {
            int c = tid;
            int row = c >> 2, cc = c & 3;
            const __hip_bfloat16* gp = W2t + (size_t)row * NH + kk + cc * 8;
            __builtin_amdgcn_global_load_lds(
                (const __attribute__((address_space(1))) void*)gp,
                (__attribute__((address_space(3))) void*)&Bs2[d][(wave * 64) * 8],
                16, 0, 0);
        }
    };

    stage(0, 0);
    __syncthreads();

    int cur = 0;
    #pragma unroll
    for (int k0 = 0; k0 < NH; k0 += 32) {
        if (k0 + 32 < NH) stage(cur ^ 1, k0 + 32);

        bf16x8 a_frag[2], b_frag[3];
        #pragma unroll
        for (int mi = 0; mi < 2; ++mi)
            a_frag[mi] = *(const bf16x8*)&As2[cur][(wave * 32 + mi * 16 + l16) * 32 + quad * 8];
        #pragma unroll
        for (int ni = 0; ni < 3; ++ni)
            b_frag[ni] = *(const bf16x8*)&Bs2[cur][(ni * 16 + l16) * 32 + quad * 8];
        #pragma unroll
        for (int mi = 0; mi < 2; ++mi)
            #pragma unroll
            for (int ni = 0; ni < 3; ++ni)
                acc[mi][ni] = __builtin_amdgcn_mfma_f32_16x16x32_bf16(
                    a_frag[mi], b_frag[ni], acc[mi][ni], 0, 0, 0);

        __syncthreads();
        cur ^= 1;
    }

    #pragma unroll
    for (int mi = 0; mi < 2; ++mi)
        #pragma unroll
        for (int v = 0; v < 4; ++v) {
            int r = m0 + wave * 32 + mi * 16 + quad * 4 + v;
            if (r < NN) {
                #pragma unroll
                for (int ni = 0; ni < 3; ++ni) {
                    int c = ni * 16 + l16;
                    H2p[(size_t)r * NC2 + c] = __float2bfloat16(acc[mi][ni][v]);
                }
            }
        }
}

// ---------------- layer-1 gather: wave per node, 4 groups x 16 lanes, 2 edges in flight ----------------
__global__ void agg1_gather(const int* __restrict__ offsets, const int2* __restrict__ erec,
                            const float* __restrict__ dinv, const __hip_bfloat16* __restrict__ H,
                            const float* __restrict__ b1, __hip_bfloat16* __restrict__ Haggb) {
    int node = (blockIdx.x * blockDim.x + threadIdx.x) >> 6;
    if (node >= NN) return;
    int lane = threadIdx.x & 63;
    int grp = lane >> 4, l16 = lane & 15;
    int beg = offsets[node], end = offsets[node + 1];
    const uint4* Hv = reinterpret_cast<const uint4*>(H);   // 8 bf16 per uint4, 16 per row
    float acc[8] = {};
    int p = beg + grp;
    for (; p + 4 < end; p += 8) {
        int2 r1 = erec[p];
        int2 r2 = erec[p + 4];
        float w1 = __int_as_float(r1.y);
        float w2 = __int_as_float(r2.y);
        uint4 h1 = Hv[(size_t)r1.x * 16 + l16];
        uint4 h2 = Hv[(size_t)r2.x * 16 + l16];
        float2 a0 = cvt2(h1.x), a1 = cvt2(h1.y), a2 = cvt2(h1.z), a3 = cvt2(h1.w);
        acc[0] += a0.x * w1; acc[1] += a0.y * w1;
        acc[2] += a1.x * w1; acc[3] += a1.y * w1;
        acc[4] += a2.x * w1; acc[5] += a2.y * w1;
        acc[6] += a3.x * w1; acc[7] += a3.y * w1;
        float2 c0 = cvt2(h2.x), c1 = cvt2(h2.y), c2 = cvt2(h2.z), c3 = cvt2(h2.w);
        acc[0] += c0.x * w2; acc[1] += c0.y * w2;
        acc[2] += c1.x * w2; acc[3] += c1.y * w2;
        acc[4] += c2.x * w2; acc[5] += c2.y * w2;
        acc[6] += c3.x * w2; acc[7] += c3.y * w2;
    }
    if (p < end) {
        int2 r = erec[p];
        float w = __int_as_float(r.y);
        uint4 hv = Hv[(size_t)r.x * 16 + l16];
        float2 f0 = cvt2(hv.x), f1 = cvt2(hv.y), f2 = cvt2(hv.z), f3 = cvt2(hv.w);
        acc[0] += f0.x * w; acc[1] += f0.y * w;
        acc[2] += f1.x * w; acc[3] += f1.y * w;
        acc[4] += f2.x * w; acc[5] += f2.y * w;
        acc[6] += f3.x * w; acc[7] += f3.y * w;
    }
    #pragma unroll
    for (int k = 0; k < 8; ++k) {
        acc[k] += __shfl_xor(acc[k], 16, 64);
        acc[k] += __shfl_xor(acc[k], 32, 64);
    }
    if (lane < 16) {
        float di = dinv[node];
        float sl = di * di;
        uint4 hs = Hv[(size_t)node * 16 + l16];
        float2 s0 = cvt2(hs.x), s1 = cvt2(hs.y), s2 = cvt2(hs.z), s3 = cvt2(hs.w);
        const float4* bb = reinterpret_cast<const float4*>(b1 + l16 * 8);
        float4 ba = bb[0], bc = bb[1];
        float o0 = fmaxf(acc[0] + s0.x * sl + ba.x, 0.f);
        float o1 = fmaxf(acc[1] + s0.y * sl + ba.y, 0.f);
        float o2 = fmaxf(acc[2] + s1.x * sl + ba.z, 0.f);
        float o3 = fmaxf(acc[3] + s1.y * sl + ba.w, 0.f);
        float o4 = fmaxf(acc[4] + s2.x * sl + bc.x, 0.f);
        float o5 = fmaxf(acc[5] + s2.y * sl + bc.y, 0.f);
        float o6 = fmaxf(acc[6] + s3.x * sl + bc.z, 0.f);
        float o7 = fmaxf(acc[7] + s3.y * sl + bc.w, 0.f);
        uint4 ov;
        ov.x = pk2(o0, o1);
        ov.y = pk2(o2, o3);
        ov.z = pk2(o4, o5);
        ov.w = pk2(o6, o7);
        *reinterpret_cast<uint4*>(Haggb + (size_t)node * NH + l16 * 8) = ov;
    }
}

// ---------------- layer-2 gather + self + bias + log_softmax (packed 48-wide H2p) ----------------
__global__ void agg2_lsm(const int* __restrict__ offsets, const int2* __restrict__ erec,
                         const float* __restrict__ dinv, const __hip_bfloat16* __restrict__ H2p,
                         const float* __restrict__ b2, float* __restrict__ out) {
    int node = (blockIdx.x * blockDim.x + threadIdx.x) >> 6;
    if (node >= NN) return;
    int lane = threadIdx.x & 63;
    int grp = lane >> 4, l16 = lane & 15;
    int beg = offsets[node], end = offsets[node + 1];
    const uint2* Hv = reinterpret_cast<const uint2*>(H2p);  // 4 bf16 per uint2, 12 per row (48 bf16)
    const bool lv = (l16 < 12);
    const uint2 zz = make_uint2(0u, 0u);
    float acc[4] = {};
    int p = beg + grp;
    for (; p + 4 < end; p += 8) {
        int2 r1 = erec[p];
        int2 r2 = erec[p + 4];
        float w1 = __int_as_float(r1.y);
        float w2 = __int_as_float(r2.y);
        uint2 h1 = lv ? Hv[(size_t)r1.x * 12 + l16] : zz;
        uint2 h2 = lv ? Hv[(size_t)r2.x * 12 + l16] : zz;
        float2 a0 = cvt2(h1.x), a1 = cvt2(h1.y);
        acc[0] += a0.x * w1; acc[1] += a0.y * w1;
        acc[2] += a1.x * w1; acc[3] += a1.y * w1;
        float2 c0 = cvt2(h2.x), c1 = cvt2(h2.y);
        acc[0] += c0.x * w2; acc[1] += c0.y * w2;
        acc[2] += c1.x * w2; acc[3] += c1.y * w2;
    }
    if (p < end) {
        int2 r = erec[p];
        float w = __int_as_float(r.y);
        uint2 hv = lv ? Hv[(size_t)r.x * 12 + l16] : zz;
        float2 f0 = cvt2(hv.x), f1 = cvt2(hv.y);
        acc[0] += f0.x * w; acc[1] += f0.y * w;
        acc[2] += f1.x * w; acc[3] += f1.y * w;
    }
    #pragma unroll
    for (int k = 0; k < 4; ++k) {
        acc[k] += __shfl_xor(acc[k], 16, 64);
        acc[k] += __shfl_xor(acc[k], 32, 64);
    }
    float v[4];
    bool valid = (l16 < 10);   // classes l16*4..l16*4+3 < 40
    if (valid) {
        float di = dinv[node];
        float sl = di * di;
        uint2 hs = Hv[(size_t)node * 12 + l16];
        float2 s0 = cvt2(hs.x), s1 = cvt2(hs.y);
        float4 bb = *reinterpret_cast<const float4*>(b2 + l16 * 4);
        v[0] = acc[0] + s0.x * sl + bb.x;
        v[1] = acc[1] + s0.y * sl + bb.y;
        v[2] = acc[2] + s1.x * sl + bb.z;
        v[3] = acc[3] + s1.y * sl + bb.w;
    } else {
        v[0] = v[1] = v[2] = v[3] = -INFINITY;
    }
    float m = fmaxf(fmaxf(v[0], v[1]), fmaxf(v[2], v[3]));
    #pragma unroll
    for (int off = 8; off; off >>= 1) m = fmaxf(m, __shfl_xor(m, off, 64));
    float ex = expf(v[0] - m) + expf(v[1] - m) + expf(v[2] - m) + expf(v[3] - m);
    #pragma unroll
    for (int off = 8; off; off >>= 1) ex += __shfl_xor(ex, off, 64);
    float ls = logf(ex);
    if (lane < 16 && valid) {
        float4 o;
        o.x = v[0] - m - ls; o.y = v[1] - m - ls;
        o.z = v[2] - m - ls; o.w = v[3] - m - ls;
        *reinterpret_cast<float4*>(out + (size_t)node * NC + l16 * 4) = o;
    }
}

extern "C" void kernel_launch(void* const* d_in, const int* in_sizes, int n_in,
                              void* d_out, int out_size, void* d_ws, size_t ws_size,
                              hipStream_t stream) {
    const float* x  = (const float*)d_in[0];
    const int*   ei = (const int*)d_in[1];
    const float* W1 = (const float*)d_in[2];
    const float* b1 = (const float*)d_in[3];
    const float* W2 = (const float*)d_in[4];
    const float* b2 = (const float*)d_in[5];
    float* out = (float*)d_out;

    int*   counts     = (int*)d_ws;
    int*   offsets    = counts + OFF_OFFSETS;
    int*   bin_cursor = counts + OFF_CURSOR;
    float* dinv       = (float*)(counts + OFF_DINV);
    int2*  erec       = (int2*)(counts + OFF_EREC);
    __hip_bfloat16* H     = (__hip_bfloat16*)(counts + OFF_H);
    __hip_bfloat16* W1t   = (__hip_bfloat16*)(counts + OFF_W1T);
    __hip_bfloat16* W2t   = (__hip_bfloat16*)(counts + OFF_W2T);
    __hip_bfloat16* Haggb = (__hip_bfloat16*)(counts + OFF_HAGG);
    int*            ebin  = counts + OFF_HAGG;   // dead before agg1 writes Haggb
    __hip_bfloat16* H2p   = H;                   // packed [NN][48] bf16, reuses H after agg1

    int* blocksums = counts + OFF_H;             // scan scratch (before gemm1 writes H)

    // 1. CSR build: count + W1t/W2t prep, then scan (offsets, dinv, bin cursor bases)
    (void)hipMemsetAsync(counts, 0, NN * sizeof(int), stream);
    count_prep<<<(NE + 255) / 256, 256, 0, stream>>>(ei + NE, counts, W1, W1t, W2, W2t);
    scan_phase1<<<SCAN_NB, SCAN_TILE, 0, stream>>>(counts, blocksums);
    scan_phase3<<<SCAN_NB, SCAN_TILE, 0, stream>>>(counts, blocksums, offsets, bin_cursor, dinv);

    // 2. FUSED+INTERLEAVED: gemm1 (MFMA, double-buffered) + pass A coarse binning
    gemm1_passA<<<GEMM1_NB + NB_A, 256, 0, stream>>>(ei, bin_cursor, ebin, x, W1t, H);

    // 2b. pass B: within-bin sort -> erec (one block per bin, L2-local writes)
    passB<<<NBINS, 256, 0, stream>>>(offsets, ebin, dinv, erec);

    // 3. layer-1 gather (fused self-loop + bias + relu) -> Haggb (bf16)
    {
        long long threads = (long long)NN * 64;
        agg1_gather<<<(unsigned)((threads + 255) / 256), 256, 0, stream>>>(
            offsets, erec, dinv, H, b1, Haggb);
    }

    // 4. H2p = bf16(Haggb @ W2[:,0:48]) via MFMA (double-buffered)
    gemm2_mfma<<<(NN + 127) / 128, 256, 0, stream>>>(Haggb, W2t, H2p);

    // 5. layer-2 gather + self + bias + log_softmax -> out
    {
        long long threads = (long long)NN * 64;
        agg2_lsm<<<(unsigned)((threads + 255) / 256), 256, 0, stream>>>(
            offsets, erec, dinv, H2p, b2, out);
    }
}

// Round 2
// 418.416 us; speedup vs baseline: 1.0122x; 1.0122x over previous
//
#include <hip/hip_runtime.h>
#include <hip/hip_bf16.h>
#include <math.h>

#define NN 100000      // nodes
#define NE 1600000     // edges
#define NF 256         // input features
#define NH 128         // hidden
#define NC 40          // classes
#define NCP 64         // padded classes for W2t (rows >=40 zero)
#define NC2 48         // packed H2p row width (classes 40..47 are zero)

// Workspace layout (4-byte units):
//   counts     [0,       100032)
//   offsets    [100032,  200128)   (NN+1 used)
//   bin_cursor [200128,  300160)   (NBINS used)
//   dinv       [300160,  400192)
//   erec       [400192,  3600192)  (NE int2)
//   H          [3600192, 10000192) (bf16 NN*NH; scan scratch early)
//   w1t        [10000192,10016576) (bf16 [128][256])
//   w2t        [10016576,10020672) (bf16 [64][128], rows >=40 zero)
//   ebin/H2p   [16400192,29200192) (ebin NE ints during passA/B; H2p bf16 [NN][48] after)
#define OFF_OFFSETS 100032
#define OFF_CURSOR  200128
#define OFF_DINV    300160
#define OFF_EREC    400192
#define OFF_H       3600192
#define OFF_W1T     10000192
#define OFF_W2T     10016576
#define OFF_HAGG    16400192

#define SCAN_TILE 1024
#define SCAN_NB   ((NN + SCAN_TILE - 1) / SCAN_TILE)   // 98

#define GEMM1_NB  ((NN + 127) / 128)    // 782
#define NBINS     ((NN + 255) / 256)    // 391
#define CHUNK_A   4096
#define NB_A      ((NE + CHUNK_A - 1) / CHUNK_A)       // 391 (= GEMM1_NB/2)

using f32x4  = __attribute__((ext_vector_type(4))) float;
using bf16x8 = __attribute__((ext_vector_type(8))) short;

// decode packed pair of bf16 (lo, hi) to fp32x2 — exact, pure bit ops
__device__ inline float2 cvt2(unsigned u) {
    float2 f;
    f.x = __uint_as_float(u << 16);
    f.y = __uint_as_float(u & 0xffff0000u);
    return f;
}

__device__ inline short bfbits(float f) {
    __hip_bfloat16 h = __float2bfloat16(f);
    return *reinterpret_cast<short*>(&h);
}

__device__ inline unsigned pk2(float lo, float hi) {
    return (unsigned)(unsigned short)bfbits(lo) | ((unsigned)(unsigned short)bfbits(hi) << 16);
}

// ---------------- count + W1t/W2t prep (fused, independent work) ----------------
__global__ void count_prep(const int* __restrict__ dst, int* __restrict__ count,
                           const float* __restrict__ W1, __hip_bfloat16* __restrict__ W1t,
                           const float* __restrict__ W2, __hip_bfloat16* __restrict__ W2t) {
    int t = blockIdx.x * blockDim.x + threadIdx.x;
    if (t < NE) atomicAdd(&count[dst[t]], 1);
    if (t < NH * NF) {
        int n = t >> 8;
        int k = t & (NF - 1);
        W1t[t] = __float2bfloat16(W1[(size_t)k * NH + n]);
    }
    if (t < NCP * NH) {
        int n = t >> 7;
        int k = t & (NH - 1);
        W2t[t] = __float2bfloat16((n < NC) ? W2[(size_t)k * NC + n] : 0.f);
    }
}

// ---- hierarchical scan (phase2 fused into phase3) ----
__global__ void scan_phase1(const int* __restrict__ count, int* __restrict__ blocksums) {
    int b = blockIdx.x, t = threadIdx.x;
    int i = b * SCAN_TILE + t;
    int v = (i < NN) ? count[i] : 0;
    #pragma unroll
    for (int off = 32; off; off >>= 1) v += __shfl_xor(v, off, 64);
    __shared__ int ws[16];
    int lane = t & 63, wave = t >> 6;
    if (lane == 0) ws[wave] = v;
    __syncthreads();
    if (t == 0) {
        int s = 0;
        #pragma unroll
        for (int w = 0; w < SCAN_TILE / 64; ++w) s += ws[w];
        blocksums[b] = s;
    }
}

// phase 3: block prefix (from blocksums) + offsets + dinv + per-bin cursor bases
__global__ void scan_phase3(const int* __restrict__ count, const int* __restrict__ blocksums,
                            int* __restrict__ offsets, int* __restrict__ bin_cursor,
                            float* __restrict__ dinv) {
    int b = blockIdx.x, t = threadIdx.x;
    int lane = t & 63, wave = t >> 6;

    // fused phase2: sum blocksums[0..b-1] using first 2 waves (SCAN_NB=98 <= 128)
    __shared__ int bsum2[2];
    if (t < 128) {
        int u = (t < b) ? blocksums[t] : 0;   // t < b <= 97 < SCAN_NB, in bounds
        #pragma unroll
        for (int off = 32; off; off >>= 1) u += __shfl_xor(u, off, 64);
        if (lane == 0) bsum2[wave] = u;
    }

    int i = b * SCAN_TILE + t;
    int v = (i < NN) ? count[i] : 0;
    int s = v;
    #pragma unroll
    for (int off = 1; off < 64; off <<= 1) {
        int u = __shfl_up(s, off, 64);
        if (lane >= off) s += u;
    }
    __shared__ int wsum[16];
    if (lane == 63) wsum[wave] = s;
    __syncthreads();
    if (t < 16) {
        int x = wsum[t];
        #pragma unroll
        for (int off = 1; off < 16; off <<= 1) {
            int u = __shfl_up(x, off, 64);
            if (t >= off) x += u;
        }
        wsum[t] = x;
    }
    __syncthreads();
    int bpref = bsum2[0] + bsum2[1];
    int excl = (s - v) + (wave ? wsum[wave - 1] : 0) + bpref;
    if (i < NN) {
        offsets[i] = excl;
        dinv[i]    = rsqrtf((float)v + 1.0f);   // +1 self loop
        if ((i & 255) == 0) bin_cursor[i >> 8] = excl;
        if (i == NN - 1) offsets[NN] = excl + v;
    }
}

// ---------------- FUSED + INTERLEAVED: layer-1 MFMA GEMM (double-buffered) + pass A ----------------
// Block pattern (3k blocks): b%3==1 -> passA chunk b/3; else gemm tile 2*(b/3)+(b%3==2)
__global__ __launch_bounds__(256, 3) void gemm1_passA(
        const int* __restrict__ ei, int* __restrict__ bin_cursor,
        int* __restrict__ ebin,
        const float* __restrict__ X, const __hip_bfloat16* __restrict__ W1t,
        __hip_bfloat16* __restrict__ H) {
    __shared__ __align__(16) int smem[12288];   // 48 KB: gemm As dbuf(32K)+Bs dbuf(16K) OR passA hist/rbase

    const int bi = blockIdx.x / 3;
    const int br = blockIdx.x % 3;

    if (br == 1) {
        // ---- pass A: partition 4096 edges into 256-node bins, run-coalesced writes ----
        int* hist  = smem;
        int* rbase = smem + NBINS;
        int e0 = bi * CHUNK_A;
        int e1 = e0 + CHUNK_A; if (e1 > NE) e1 = NE;
        for (int j = threadIdx.x; j < NBINS; j += 256) hist[j] = 0;
        __syncthreads();
        for (int p = e0 + threadIdx.x; p < e1; p += 256)
            atomicAdd(&hist[ei[NE + p] >> 8], 1);
        __syncthreads();
        for (int j = threadIdx.x; j < NBINS; j += 256) {
            int c = hist[j];
            rbase[j] = c ? atomicAdd(&bin_cursor[j], c) : 0;
        }
        __syncthreads();
        for (int p = e0 + threadIdx.x; p < e1; p += 256) {
            int s = ei[p];
            int d = ei[NE + p];
            int bb = d >> 8;
            int pos = atomicAdd(&rbase[bb], 1);
            ebin[pos] = s | ((d & 255) << 17);
        }
        return;
    }

    // ---- gemm1 path: H = bf16(x @ W1), 128x128 tile, 2-phase double-buffered K-loop ----
    float* As = (float*)smem;           // 2 x [128][32] fp32 (buf stride 4096 floats)
    short* Bs = (short*)(smem + 8192);  // 2 x [128][32] bf16 (buf stride 4096 shorts)

    const int tid  = threadIdx.x;
    const int wave = tid >> 6;
    const int lane = tid & 63;
    const int quad = lane >> 4;
    const int l16  = lane & 15;
    const int wy = wave >> 1, wx = wave & 1;
    const int m0 = (bi * 2 + (br == 2 ? 1 : 0)) * 128;

    f32x4 acc[4][4] = {};

    auto stage = [&](int d, int kk) {
        #pragma unroll
        for (int i = 0; i < 4; ++i) {
            int c   = i * 256 + tid;
            int row = c >> 3, cc = c & 7;
            int gr  = m0 + row; if (gr > NN - 1) gr = NN - 1;
            const float* gp = X + (size_t)gr * NF + kk + cc * 4;
            __builtin_amdgcn_global_load_lds(
                (const __attribute__((address_space(1))) void*)gp,
                (__attribute__((address_space(3))) void*)&As[d * 4096 + (i * 256 + wave * 64) * 4],
                16, 0, 0);
        }
        #pragma unroll
        for (int i = 0; i < 2; ++i) {
            int c = i * 256 + tid;
            int n = c >> 2, cc = c & 3;
            const __hip_bfloat16* gp = W1t + (size_t)n * NF + kk + cc * 8;
            __builtin_amdgcn_global_load_lds(
                (const __attribute__((address_space(1))) void*)gp,
                (__attribute__((address_space(3))) void*)&Bs[d * 4096 + (i * 256 + wave * 64) * 8],
                16, 0, 0);
        }
    };

    // prologue: fill buffer 0, drain, barrier
    stage(0, 0);
    __syncthreads();

    int cur = 0;
    #pragma unroll
    for (int k0 = 0; k0 < NF; k0 += 32) {
        if (k0 + 32 < NF) stage(cur ^ 1, k0 + 32);   // prefetch next tile (in flight during MFMA)

        bf16x8 a_frag[4], b_frag[4];
        #pragma unroll
        for (int mi = 0; mi < 4; ++mi) {
            const float* ap = &As[cur * 4096 + (wy * 64 + mi * 16 + l16) * 32 + quad * 8];
            f32x4 a0 = *(const f32x4*)ap;
            f32x4 a1 = *(const f32x4*)(ap + 4);
            bf16x8 af;
            af[0] = bfbits(a0.x); af[1] = bfbits(a0.y);
            af[2] = bfbits(a0.z); af[3] = bfbits(a0.w);
            af[4] = bfbits(a1.x); af[5] = bfbits(a1.y);
            af[6] = bfbits(a1.z); af[7] = bfbits(a1.w);
            a_frag[mi] = af;
        }
        #pragma unroll
        for (int ni = 0; ni < 4; ++ni) {
            const short* bp = &Bs[cur * 4096 + (wx * 64 + ni * 16 + l16) * 32 + quad * 8];
            b_frag[ni] = *(const bf16x8*)bp;
        }
        #pragma unroll
        for (int mi = 0; mi < 4; ++mi)
            #pragma unroll
            for (int ni = 0; ni < 4; ++ni)
                acc[mi][ni] = __builtin_amdgcn_mfma_f32_16x16x32_bf16(
                    a_frag[mi], b_frag[ni], acc[mi][ni], 0, 0, 0);

        __syncthreads();   // drains this iter's prefetch (vmcnt 0) + protects buffer swap
        cur ^= 1;
    }

    #pragma unroll
    for (int mi = 0; mi < 4; ++mi)
        #pragma unroll
        for (int v = 0; v < 4; ++v) {
            int r = m0 + wy * 64 + mi * 16 + quad * 4 + v;
            if (r < NN) {
                #pragma unroll
                for (int ni = 0; ni < 4; ++ni) {
                    int c = wx * 64 + ni * 16 + l16;
                    H[(size_t)r * NH + c] = __float2bfloat16(acc[mi][ni][v]);
                }
            }
        }
}

// ---------------- pass B: within-bin counting sort -> erec (L2-local writes) ----------------
__global__ __launch_bounds__(256) void passB(const int* __restrict__ offsets,
                                             const int* __restrict__ ebin,
                                             const float* __restrict__ dinv,
                                             int2* __restrict__ erec) {
    int b = blockIdx.x;
    int n0 = b << 8;
    int nodes = NN - n0; if (nodes > 256) nodes = 256;
    __shared__ int cur[256];
    __shared__ float dls[256];
    if (threadIdx.x < nodes) {
        cur[threadIdx.x] = offsets[n0 + threadIdx.x];
        dls[threadIdx.x] = dinv[n0 + threadIdx.x];
    }
    __syncthreads();
    int binstart = offsets[n0];
    int binend   = offsets[n0 + nodes];
    for (int p = binstart + threadIdx.x; p < binend; p += 256) {
        int e  = ebin[p];
        int s  = e & 0x1FFFF;
        int dl = e >> 17;
        int pos = atomicAdd(&cur[dl], 1);
        float w = dinv[s] * dls[dl];
        erec[pos] = make_int2(s, __float_as_int(w));
    }
}

// ---------------- FUSED: layer-1 gather (group-per-node) + layer-2 GEMM from LDS ----------------
// Block b: aggregate nodes [128b,128b+128) into a 32KB bf16 LDS tile (XOR-swizzled),
// then H2p[tile] = bf16(tile @ W2[:,0:48]) via MFMA with W2 fragments in registers.
// Removes the Haggb global round-trip (25.6MB write + 25.6MB read) and the gemm2 launch.
__global__ __launch_bounds__(256) void agg1_gemm2(
        const int* __restrict__ offsets, const int2* __restrict__ erec,
        const float* __restrict__ dinv, const __hip_bfloat16* __restrict__ H,
        const float* __restrict__ b1, const __hip_bfloat16* __restrict__ W2t,
        __hip_bfloat16* __restrict__ H2p) {
    __shared__ __align__(16) short As[128 * 128];   // 32 KB swizzled Hagg tile
    const int tid  = threadIdx.x;
    const int wave = tid >> 6;
    const int lane = tid & 63;
    const int quad = lane >> 4;     // == gather group id
    const int l16  = lane & 15;
    const int m0   = blockIdx.x * 128;
    const char* Hb = (const char*)H;
    const unsigned lb = (unsigned)(l16 << 4);

    // ---- phase 1: each 16-lane group owns one node, 4 gather loads in flight ----
    #pragma unroll 1
    for (int rd = 0; rd < 8; ++rd) {
        int nl = wave * 32 + rd * 4 + quad;
        int node = m0 + nl;
        if (node < NN) {
            int beg = offsets[node], end = offsets[node + 1];
            float ac[8] = {};
            for (int p = beg; p < end; p += 4) {
                int2 e0 = erec[p];
                int2 e1 = (p + 1 < end) ? erec[p + 1] : make_int2(0, 0);
                int2 e2 = (p + 2 < end) ? erec[p + 2] : make_int2(0, 0);
                int2 e3 = (p + 3 < end) ? erec[p + 3] : make_int2(0, 0);
                uint4 h0 = *(const uint4*)(Hb + (((unsigned)e0.x) << 8) + lb);
                uint4 h1 = *(const uint4*)(Hb + (((unsigned)e1.x) << 8) + lb);
                uint4 h2 = *(const uint4*)(Hb + (((unsigned)e2.x) << 8) + lb);
                uint4 h3 = *(const uint4*)(Hb + (((unsigned)e3.x) << 8) + lb);
                float w0 = __int_as_float(e0.y), w1 = __int_as_float(e1.y);
                float w2 = __int_as_float(e2.y), w3 = __int_as_float(e3.y);
                #define ACC8(hv, ww) { \
                    float2 q0 = cvt2(hv.x), q1 = cvt2(hv.y), q2 = cvt2(hv.z), q3 = cvt2(hv.w); \
                    ac[0] += q0.x * (ww); ac[1] += q0.y * (ww); \
                    ac[2] += q1.x * (ww); ac[3] += q1.y * (ww); \
                    ac[4] += q2.x * (ww); ac[5] += q2.y * (ww); \
                    ac[6] += q3.x * (ww); ac[7] += q3.y * (ww); }
                ACC8(h0, w0) ACC8(h1, w1) ACC8(h2, w2) ACC8(h3, w3)
                #undef ACC8
            }
            // self loop + bias + relu -> bf16 row in LDS
            float di = dinv[node];
            float sl = di * di;
            uint4 hs = *(const uint4*)(Hb + (((unsigned)node) << 8) + lb);
            float2 s0 = cvt2(hs.x), s1 = cvt2(hs.y), s2 = cvt2(hs.z), s3 = cvt2(hs.w);
            const float4* bb = reinterpret_cast<const float4*>(b1 + l16 * 8);
            float4 ba = bb[0], bc = bb[1];
            float o0 = fmaxf(ac[0] + s0.x * sl + ba.x, 0.f);
            float o1 = fmaxf(ac[1] + s0.y * sl + ba.y, 0.f);
            float o2 = fmaxf(ac[2] + s1.x * sl + ba.z, 0.f);
            float o3 = fmaxf(ac[3] + s1.y * sl + ba.w, 0.f);
            float o4 = fmaxf(ac[4] + s2.x * sl + bc.x, 0.f);
            float o5 = fmaxf(ac[5] + s2.y * sl + bc.y, 0.f);
            float o6 = fmaxf(ac[6] + s3.x * sl + bc.z, 0.f);
            float o7 = fmaxf(ac[7] + s3.y * sl + bc.w, 0.f);
            uint4 ov;
            ov.x = pk2(o0, o1);
            ov.y = pk2(o2, o3);
            ov.z = pk2(o4, o5);
            ov.w = pk2(o6, o7);
            unsigned cb = lb ^ (((unsigned)nl & 7u) << 4);   // XOR-swizzle (G4)
            *reinterpret_cast<uint4*>((char*)As + nl * 256 + cb) = ov;
        }
    }

    // ---- W2 fragments to registers (16KB, L2-hot; 48 VGPRs, phase-2 only) ----
    bf16x8 bfr[4][3];
    #pragma unroll
    for (int ks = 0; ks < 4; ++ks)
        #pragma unroll
        for (int ni = 0; ni < 3; ++ni)
            bfr[ks][ni] = *(const bf16x8*)(W2t + (size_t)(ni * 16 + l16) * NH + ks * 32 + quad * 8);

    __syncthreads();

    // ---- phase 2: 128x48x128 MFMA from LDS ----
    f32x4 acc2[2][3] = {};
    #pragma unroll
    for (int ks = 0; ks < 4; ++ks) {
        bf16x8 afr[2];
        #pragma unroll
        for (int mi = 0; mi < 2; ++mi) {
            int row = wave * 32 + mi * 16 + l16;
            unsigned cb = ((unsigned)(ks * 64 + quad * 16)) ^ (((unsigned)row & 7u) << 4);
            afr[mi] = *(const bf16x8*)((const char*)As + row * 256 + cb);
        }
        #pragma unroll
        for (int mi = 0; mi < 2; ++mi)
            #pragma unroll
            for (int ni = 0; ni < 3; ++ni)
                acc2[mi][ni] = __builtin_amdgcn_mfma_f32_16x16x32_bf16(
                    afr[mi], bfr[ks][ni], acc2[mi][ni], 0, 0, 0);
    }

    #pragma unroll
    for (int mi = 0; mi < 2; ++mi)
        #pragma unroll
        for (int v = 0; v < 4; ++v) {
            int r = m0 + wave * 32 + mi * 16 + quad * 4 + v;
            if (r < NN) {
                #pragma unroll
                for (int ni = 0; ni < 3; ++ni) {
                    int c = ni * 16 + l16;
                    H2p[(size_t)r * NC2 + c] = __float2bfloat16(acc2[mi][ni][v]);
                }
            }
        }
}

// ---------------- layer-2 gather (group-per-node) + self + bias + log_softmax ----------------
__global__ void agg2_lsm(const int* __restrict__ offsets, const int2* __restrict__ erec,
                         const float* __restrict__ dinv, const __hip_bfloat16* __restrict__ H2p,
                         const float* __restrict__ b2, float* __restrict__ out) {
    int node = (blockIdx.x * blockDim.x + threadIdx.x) >> 4;
    if (node >= NN) return;
    int l16 = threadIdx.x & 15;
    const char* Hb = (const char*)H2p;
    const bool lv = (l16 < 12);      // 12 lanes x 8B = 96B = 48 bf16 row
    const unsigned lo = (unsigned)(l16 * 8);
    const uint2 zz = make_uint2(0u, 0u);
    float a0 = 0.f, a1 = 0.f, a2 = 0.f, a3 = 0.f;
    int beg = offsets[node], end = offsets[node + 1];
    for (int p = beg; p < end; p += 4) {
        int2 e0 = erec[p];
        int2 e1 = (p + 1 < end) ? erec[p + 1] : make_int2(0, 0);
        int2 e2 = (p + 2 < end) ? erec[p + 2] : make_int2(0, 0);
        int2 e3 = (p + 3 < end) ? erec[p + 3] : make_int2(0, 0);
        uint2 h0 = lv ? *(const uint2*)(Hb + ((unsigned)e0.x & 0x1FFFFu) * 96u + lo) : zz;
        uint2 h1 = lv ? *(const uint2*)(Hb + ((unsigned)e1.x & 0x1FFFFu) * 96u + lo) : zz;
        uint2 h2 = lv ? *(const uint2*)(Hb + ((unsigned)e2.x & 0x1FFFFu) * 96u + lo) : zz;
        uint2 h3 = lv ? *(const uint2*)(Hb + ((unsigned)e3.x & 0x1FFFFu) * 96u + lo) : zz;
        float w0 = __int_as_float(e0.y), w1 = __int_as_float(e1.y);
        float w2 = __int_as_float(e2.y), w3 = __int_as_float(e3.y);
        #define ACC4(hv, ww) { \
            float2 q0 = cvt2(hv.x), q1 = cvt2(hv.y); \
            a0 += q0.x * (ww); a1 += q0.y * (ww); \
            a2 += q1.x * (ww); a3 += q1.y * (ww); }
        ACC4(h0, w0) ACC4(h1, w1) ACC4(h2, w2) ACC4(h3, w3)
        #undef ACC4
    }
    float v0, v1, v2, v3;
    bool valid = (l16 < 10);   // classes l16*4..l16*4+3 < 40
    if (valid) {
        float di = dinv[node];
        float sl = di * di;
        uint2 hs = *(const uint2*)(Hb + ((unsigned)node & 0x1FFFFu) * 96u + lo);
        float2 s0 = cvt2(hs.x), s1 = cvt2(hs.y);
        float4 bb = *reinterpret_cast<const float4*>(b2 + l16 * 4);
        v0 = a0 + s0.x * sl + bb.x;
        v1 = a1 + s0.y * sl + bb.y;
        v2 = a2 + s1.x * sl + bb.z;
        v3 = a3 + s1.y * sl + bb.w;
    } else {
        v0 = v1 = v2 = v3 = -INFINITY;
    }
    float m = fmaxf(fmaxf(v0, v1), fmaxf(v2, v3));
    #pragma unroll
    for (int off = 8; off; off >>= 1) m = fmaxf(m, __shfl_xor(m, off, 64));
    float ex = expf(v0 - m) + expf(v1 - m) + expf(v2 - m) + expf(v3 - m);
    #pragma unroll
    for (int off = 8; off; off >>= 1) ex += __shfl_xor(ex, off, 64);
    float ls = logf(ex);
    if (valid) {
        float4 o;
        o.x = v0 - m - ls; o.y = v1 - m - ls;
        o.z = v2 - m - ls; o.w = v3 - m - ls;
        *reinterpret_cast<float4*>(out + (size_t)node * NC + l16 * 4) = o;
    }
}

extern "C" void kernel_launch(void* const* d_in, const int* in_sizes, int n_in,
                              void* d_out, int out_size, void* d_ws, size_t ws_size,
                              hipStream_t stream) {
    const float* x  = (const float*)d_in[0];
    const int*   ei = (const int*)d_in[1];
    const float* W1 = (const float*)d_in[2];
    const float* b1 = (const float*)d_in[3];
    const float* W2 = (const float*)d_in[4];
    const float* b2 = (const float*)d_in[5];
    float* out = (float*)d_out;

    int*   counts     = (int*)d_ws;
    int*   offsets    = counts + OFF_OFFSETS;
    int*   bin_cursor = counts + OFF_CURSOR;
    float* dinv       = (float*)(counts + OFF_DINV);
    int2*  erec       = (int2*)(counts + OFF_EREC);
    __hip_bfloat16* H     = (__hip_bfloat16*)(counts + OFF_H);
    __hip_bfloat16* W1t   = (__hip_bfloat16*)(counts + OFF_W1T);
    __hip_bfloat16* W2t   = (__hip_bfloat16*)(counts + OFF_W2T);
    int*            ebin  = counts + OFF_HAGG;                    // dead after passB
    __hip_bfloat16* H2p   = (__hip_bfloat16*)(counts + OFF_HAGG); // packed [NN][48] bf16, reuses ebin

    int* blocksums = counts + OFF_H;             // scan scratch (before gemm1 writes H)

    // 1. CSR build: count + W1t/W2t prep, then scan (offsets, dinv, bin cursor bases)
    (void)hipMemsetAsync(counts, 0, NN * sizeof(int), stream);
    count_prep<<<(NE + 255) / 256, 256, 0, stream>>>(ei + NE, counts, W1, W1t, W2, W2t);
    scan_phase1<<<SCAN_NB, SCAN_TILE, 0, stream>>>(counts, blocksums);
    scan_phase3<<<SCAN_NB, SCAN_TILE, 0, stream>>>(counts, blocksums, offsets, bin_cursor, dinv);

    // 2. FUSED+INTERLEAVED: gemm1 (MFMA, double-buffered) + pass A coarse binning
    gemm1_passA<<<GEMM1_NB + NB_A, 256, 0, stream>>>(ei, bin_cursor, ebin, x, W1t, H);

    // 2b. pass B: within-bin sort -> erec (one block per bin, L2-local writes)
    passB<<<NBINS, 256, 0, stream>>>(offsets, ebin, dinv, erec);

    // 3. FUSED layer-1 gather + layer-2 GEMM -> H2p (no Haggb round-trip)
    agg1_gemm2<<<(NN + 127) / 128, 256, 0, stream>>>(offsets, erec, dinv, H, b1, W2t, H2p);

    // 4. layer-2 gather + self + bias + log_softmax -> out
    {
        long long threads = (long long)NN * 16;
        agg2_lsm<<<(unsigned)((threads + 255) / 256), 256, 0, stream>>>(
            offsets, erec, dinv, H2p, b2, out);
    }
}

// Round 3
// 411.024 us; speedup vs baseline: 1.0304x; 1.0180x over previous
//
#include <hip/hip_runtime.h>
#include <hip/hip_bf16.h>
#include <math.h>

#define NN 100000      // nodes
#define NE 1600000     // edges
#define NF 256         // input features
#define NH 128         // hidden
#define NC 40          // classes
#define NCP 64         // padded classes for W2t (rows >=40 zero)
#define NC2 48         // packed H2p row width (classes 40..47 are zero)

// Workspace layout (4-byte units):
//   counts     [0,       100032)
//   offsets    [100032,  200128)   (NN+1 used)
//   bin_cursor [200128,  300160)   (NBINS used)
//   dinv       [300160,  400192)
//   erec       [400192,  3600192)  (NE int2)
//   H          [3600192, 10000192) (bf16 NN*NH; scan scratch early)
//   w1t        [10000192,10016576) (bf16 [128][256])
//   w2t        [10016576,10020672) (bf16 [64][128], rows >=40 zero)
//   ebin/H2p   [16400192,29200192) (ebin NE ints during passA/B; H2p bf16 [NN][48] after)
#define OFF_OFFSETS 100032
#define OFF_CURSOR  200128
#define OFF_DINV    300160
#define OFF_EREC    400192
#define OFF_H       3600192
#define OFF_W1T     10000192
#define OFF_W2T     10016576
#define OFF_HAGG    16400192

#define SCAN_TILE 1024
#define SCAN_NB   ((NN + SCAN_TILE - 1) / SCAN_TILE)   // 98

#define GEMM1_NB  ((NN + 127) / 128)    // 782
#define NBINS     ((NN + 255) / 256)    // 391
#define CHUNK_A   4096
#define NB_A      ((NE + CHUNK_A - 1) / CHUNK_A)       // 391 (= GEMM1_NB/2)

using f32x4  = __attribute__((ext_vector_type(4))) float;
using bf16x8 = __attribute__((ext_vector_type(8))) short;

// decode packed pair of bf16 (lo, hi) to fp32x2 — exact, pure bit ops
__device__ inline float2 cvt2(unsigned u) {
    float2 f;
    f.x = __uint_as_float(u << 16);
    f.y = __uint_as_float(u & 0xffff0000u);
    return f;
}

__device__ inline short bfbits(float f) {
    __hip_bfloat16 h = __float2bfloat16(f);
    return *reinterpret_cast<short*>(&h);
}

__device__ inline unsigned pk2(float lo, float hi) {
    return (unsigned)(unsigned short)bfbits(lo) | ((unsigned)(unsigned short)bfbits(hi) << 16);
}

// ---------------- count + W1t/W2t prep (fused, independent work) ----------------
__global__ void count_prep(const int* __restrict__ dst, int* __restrict__ count,
                           const float* __restrict__ W1, __hip_bfloat16* __restrict__ W1t,
                           const float* __restrict__ W2, __hip_bfloat16* __restrict__ W2t) {
    int t = blockIdx.x * blockDim.x + threadIdx.x;
    if (t < NE) atomicAdd(&count[dst[t]], 1);
    if (t < NH * NF) {
        int n = t >> 8;
        int k = t & (NF - 1);
        W1t[t] = __float2bfloat16(W1[(size_t)k * NH + n]);
    }
    if (t < NCP * NH) {
        int n = t >> 7;
        int k = t & (NH - 1);
        W2t[t] = __float2bfloat16((n < NC) ? W2[(size_t)k * NC + n] : 0.f);
    }
}

// ---- hierarchical scan (phase2 fused into phase3) ----
__global__ void scan_phase1(const int* __restrict__ count, int* __restrict__ blocksums) {
    int b = blockIdx.x, t = threadIdx.x;
    int i = b * SCAN_TILE + t;
    int v = (i < NN) ? count[i] : 0;
    #pragma unroll
    for (int off = 32; off; off >>= 1) v += __shfl_xor(v, off, 64);
    __shared__ int ws[16];
    int lane = t & 63, wave = t >> 6;
    if (lane == 0) ws[wave] = v;
    __syncthreads();
    if (t == 0) {
        int s = 0;
        #pragma unroll
        for (int w = 0; w < SCAN_TILE / 64; ++w) s += ws[w];
        blocksums[b] = s;
    }
}

// phase 3: block prefix (from blocksums) + offsets + dinv + per-bin cursor bases
__global__ void scan_phase3(const int* __restrict__ count, const int* __restrict__ blocksums,
                            int* __restrict__ offsets, int* __restrict__ bin_cursor,
                            float* __restrict__ dinv) {
    int b = blockIdx.x, t = threadIdx.x;
    int lane = t & 63, wave = t >> 6;

    // fused phase2: sum blocksums[0..b-1] using first 2 waves (SCAN_NB=98 <= 128)
    __shared__ int bsum2[2];
    if (t < 128) {
        int u = (t < b) ? blocksums[t] : 0;   // t < b <= 97 < SCAN_NB, in bounds
        #pragma unroll
        for (int off = 32; off; off >>= 1) u += __shfl_xor(u, off, 64);
        if (lane == 0) bsum2[wave] = u;
    }

    int i = b * SCAN_TILE + t;
    int v = (i < NN) ? count[i] : 0;
    int s = v;
    #pragma unroll
    for (int off = 1; off < 64; off <<= 1) {
        int u = __shfl_up(s, off, 64);
        if (lane >= off) s += u;
    }
    __shared__ int wsum[16];
    if (lane == 63) wsum[wave] = s;
    __syncthreads();
    if (t < 16) {
        int x = wsum[t];
        #pragma unroll
        for (int off = 1; off < 16; off <<= 1) {
            int u = __shfl_up(x, off, 64);
            if (t >= off) x += u;
        }
        wsum[t] = x;
    }
    __syncthreads();
    int bpref = bsum2[0] + bsum2[1];
    int excl = (s - v) + (wave ? wsum[wave - 1] : 0) + bpref;
    if (i < NN) {
        offsets[i] = excl;
        dinv[i]    = rsqrtf((float)v + 1.0f);   // +1 self loop
        if ((i & 255) == 0) bin_cursor[i >> 8] = excl;
        if (i == NN - 1) offsets[NN] = excl + v;
    }
}

// ---------------- FUSED + INTERLEAVED: layer-1 MFMA GEMM (512 thr, dbuf) + pass A ----------------
// Block pattern (3k blocks): b%3==1 -> passA chunk b/3; else gemm tile 2*(b/3)+(b%3==2)
// 512 threads/block: 8 waves per tile -> ~24 waves/CU at 3 blocks/CU (LDS-capped), vs 12 before.
__global__ __launch_bounds__(512, 4) void gemm1_passA(
        const int* __restrict__ ei, int* __restrict__ bin_cursor,
        int* __restrict__ ebin,
        const float* __restrict__ X, const __hip_bfloat16* __restrict__ W1t,
        __hip_bfloat16* __restrict__ H) {
    __shared__ __align__(16) int smem[12288];   // 48 KB: gemm As dbuf(32K)+Bs dbuf(16K) OR passA hist/rbase

    const int bi = blockIdx.x / 3;
    const int br = blockIdx.x % 3;

    if (br == 1) {
        // ---- pass A: partition 4096 edges into 256-node bins, run-coalesced writes ----
        int* hist  = smem;
        int* rbase = smem + NBINS;
        int e0 = bi * CHUNK_A;
        int e1 = e0 + CHUNK_A; if (e1 > NE) e1 = NE;
        for (int j = threadIdx.x; j < NBINS; j += 512) hist[j] = 0;
        __syncthreads();
        for (int p = e0 + threadIdx.x; p < e1; p += 512)
            atomicAdd(&hist[ei[NE + p] >> 8], 1);
        __syncthreads();
        for (int j = threadIdx.x; j < NBINS; j += 512) {
            int c = hist[j];
            rbase[j] = c ? atomicAdd(&bin_cursor[j], c) : 0;
        }
        __syncthreads();
        for (int p = e0 + threadIdx.x; p < e1; p += 512) {
            int s = ei[p];
            int d = ei[NE + p];
            int bb = d >> 8;
            int pos = atomicAdd(&rbase[bb], 1);
            ebin[pos] = s | ((d & 255) << 17);
        }
        return;
    }

    // ---- gemm1 path: H = bf16(x @ W1), 128x128 tile, 8 waves, dbuf K-loop ----
    float* As = (float*)smem;           // 2 x [128][32] fp32 (buf stride 4096 floats)
    short* Bs = (short*)(smem + 8192);  // 2 x [128][32] bf16 (buf stride 4096 shorts)

    const int tid  = threadIdx.x;
    const int wave = tid >> 6;
    const int lane = tid & 63;
    const int quad = lane >> 4;
    const int l16  = lane & 15;
    const int wy = wave >> 1, wx = wave & 1;    // wy 0..3 (rows), wx 0..1 (cols)
    const int m0 = (bi * 2 + (br == 2 ? 1 : 0)) * 128;

    f32x4 acc[2][4] = {};

    auto stage = [&](int d, int kk) {
        // As: 1024 x 16B chunks, 2 per thread
        #pragma unroll
        for (int i = 0; i < 2; ++i) {
            int c   = i * 512 + tid;
            int row = c >> 3, cc = c & 7;
            int gr  = m0 + row; if (gr > NN - 1) gr = NN - 1;
            const float* gp = X + (size_t)gr * NF + kk + cc * 4;
            __builtin_amdgcn_global_load_lds(
                (const __attribute__((address_space(1))) void*)gp,
                (__attribute__((address_space(3))) void*)&As[d * 4096 + (i * 512 + wave * 64) * 4],
                16, 0, 0);
        }
        // Bs: 512 x 16B chunks, 1 per thread
        {
            int n = tid >> 2, cc = tid & 3;
            const __hip_bfloat16* gp = W1t + (size_t)n * NF + kk + cc * 8;
            __builtin_amdgcn_global_load_lds(
                (const __attribute__((address_space(1))) void*)gp,
                (__attribute__((address_space(3))) void*)&Bs[d * 4096 + (wave * 64) * 8],
                16, 0, 0);
        }
    };

    // prologue: fill buffer 0, drain, barrier
    stage(0, 0);
    __syncthreads();

    int cur = 0;
    #pragma unroll
    for (int k0 = 0; k0 < NF; k0 += 32) {
        if (k0 + 32 < NF) stage(cur ^ 1, k0 + 32);   // prefetch next tile (in flight during MFMA)

        bf16x8 a_frag[2], b_frag[4];
        #pragma unroll
        for (int mi = 0; mi < 2; ++mi) {
            const float* ap = &As[cur * 4096 + (wy * 32 + mi * 16 + l16) * 32 + quad * 8];
            f32x4 a0 = *(const f32x4*)ap;
            f32x4 a1 = *(const f32x4*)(ap + 4);
            bf16x8 af;
            af[0] = bfbits(a0.x); af[1] = bfbits(a0.y);
            af[2] = bfbits(a0.z); af[3] = bfbits(a0.w);
            af[4] = bfbits(a1.x); af[5] = bfbits(a1.y);
            af[6] = bfbits(a1.z); af[7] = bfbits(a1.w);
            a_frag[mi] = af;
        }
        #pragma unroll
        for (int ni = 0; ni < 4; ++ni) {
            const short* bp = &Bs[cur * 4096 + (wx * 64 + ni * 16 + l16) * 32 + quad * 8];
            b_frag[ni] = *(const bf16x8*)bp;
        }
        #pragma unroll
        for (int mi = 0; mi < 2; ++mi)
            #pragma unroll
            for (int ni = 0; ni < 4; ++ni)
                acc[mi][ni] = __builtin_amdgcn_mfma_f32_16x16x32_bf16(
                    a_frag[mi], b_frag[ni], acc[mi][ni], 0, 0, 0);

        __syncthreads();   // drains this iter's prefetch (vmcnt 0) + protects buffer swap
        cur ^= 1;
    }

    #pragma unroll
    for (int mi = 0; mi < 2; ++mi)
        #pragma unroll
        for (int v = 0; v < 4; ++v) {
            int r = m0 + wy * 32 + mi * 16 + quad * 4 + v;
            if (r < NN) {
                #pragma unroll
                for (int ni = 0; ni < 4; ++ni) {
                    int c = wx * 64 + ni * 16 + l16;
                    H[(size_t)r * NH + c] = __float2bfloat16(acc[mi][ni][v]);
                }
            }
        }
}

// ---------------- pass B: within-bin counting sort -> erec (L2-local writes) ----------------
__global__ __launch_bounds__(256) void passB(const int* __restrict__ offsets,
                                             const int* __restrict__ ebin,
                                             const float* __restrict__ dinv,
                                             int2* __restrict__ erec) {
    int b = blockIdx.x;
    int n0 = b << 8;
    int nodes = NN - n0; if (nodes > 256) nodes = 256;
    __shared__ int cur[256];
    __shared__ float dls[256];
    if (threadIdx.x < nodes) {
        cur[threadIdx.x] = offsets[n0 + threadIdx.x];
        dls[threadIdx.x] = dinv[n0 + threadIdx.x];
    }
    __syncthreads();
    int binstart = offsets[n0];
    int binend   = offsets[n0 + nodes];
    for (int p = binstart + threadIdx.x; p < binend; p += 256) {
        int e  = ebin[p];
        int s  = e & 0x1FFFF;
        int dl = e >> 17;
        int pos = atomicAdd(&cur[dl], 1);
        float w = dinv[s] * dls[dl];
        erec[pos] = make_int2(s, __float_as_int(w));
    }
}

// ---------------- FUSED: layer-1 gather (group-per-node) + layer-2 GEMM from LDS ----------------
// 512 threads/block: 32 gather groups x 4 nodes; MFMA phase 8 waves x 16 rows.
// 32KB LDS -> up to 4 resident blocks/CU = 32 waves (vs 12 at 256 thr).
__global__ __launch_bounds__(512, 4) void agg1_gemm2(
        const int* __restrict__ offsets, const int2* __restrict__ erec,
        const float* __restrict__ dinv, const __hip_bfloat16* __restrict__ H,
        const float* __restrict__ b1, const __hip_bfloat16* __restrict__ W2t,
        __hip_bfloat16* __restrict__ H2p) {
    __shared__ __align__(16) short As[128 * 128];   // 32 KB swizzled Hagg tile
    const int tid  = threadIdx.x;
    const int wave = tid >> 6;
    const int lane = tid & 63;
    const int quad = lane >> 4;
    const int l16  = lane & 15;
    const int grp  = tid >> 4;      // 0..31 gather group
    const int m0   = blockIdx.x * 128;
    const char* Hb = (const char*)H;
    const unsigned lb = (unsigned)(l16 << 4);

    // ---- phase 1: each 16-lane group owns one node, 4 gather loads in flight ----
    #pragma unroll 1
    for (int rd = 0; rd < 4; ++rd) {
        int nl = rd * 32 + grp;
        int node = m0 + nl;
        if (node < NN) {
            int beg = offsets[node], end = offsets[node + 1];
            float ac[8] = {};
            for (int p = beg; p < end; p += 4) {
                int2 e0 = erec[p];
                int2 e1 = (p + 1 < end) ? erec[p + 1] : make_int2(0, 0);
                int2 e2 = (p + 2 < end) ? erec[p + 2] : make_int2(0, 0);
                int2 e3 = (p + 3 < end) ? erec[p + 3] : make_int2(0, 0);
                uint4 h0 = *(const uint4*)(Hb + (((unsigned)e0.x) << 8) + lb);
                uint4 h1 = *(const uint4*)(Hb + (((unsigned)e1.x) << 8) + lb);
                uint4 h2 = *(const uint4*)(Hb + (((unsigned)e2.x) << 8) + lb);
                uint4 h3 = *(const uint4*)(Hb + (((unsigned)e3.x) << 8) + lb);
                float w0 = __int_as_float(e0.y), w1 = __int_as_float(e1.y);
                float w2 = __int_as_float(e2.y), w3 = __int_as_float(e3.y);
                #define ACC8(hv, ww) { \
                    float2 q0 = cvt2(hv.x), q1 = cvt2(hv.y), q2 = cvt2(hv.z), q3 = cvt2(hv.w); \
                    ac[0] += q0.x * (ww); ac[1] += q0.y * (ww); \
                    ac[2] += q1.x * (ww); ac[3] += q1.y * (ww); \
                    ac[4] += q2.x * (ww); ac[5] += q2.y * (ww); \
                    ac[6] += q3.x * (ww); ac[7] += q3.y * (ww); }
                ACC8(h0, w0) ACC8(h1, w1) ACC8(h2, w2) ACC8(h3, w3)
                #undef ACC8
            }
            // self loop + bias + relu -> bf16 row in LDS
            float di = dinv[node];
            float sl = di * di;
            uint4 hs = *(const uint4*)(Hb + (((unsigned)node) << 8) + lb);
            float2 s0 = cvt2(hs.x), s1 = cvt2(hs.y), s2 = cvt2(hs.z), s3 = cvt2(hs.w);
            const float4* bb = reinterpret_cast<const float4*>(b1 + l16 * 8);
            float4 ba = bb[0], bc = bb[1];
            float o0 = fmaxf(ac[0] + s0.x * sl + ba.x, 0.f);
            float o1 = fmaxf(ac[1] + s0.y * sl + ba.y, 0.f);
            float o2 = fmaxf(ac[2] + s1.x * sl + ba.z, 0.f);
            float o3 = fmaxf(ac[3] + s1.y * sl + ba.w, 0.f);
            float o4 = fmaxf(ac[4] + s2.x * sl + bc.x, 0.f);
            float o5 = fmaxf(ac[5] + s2.y * sl + bc.y, 0.f);
            float o6 = fmaxf(ac[6] + s3.x * sl + bc.z, 0.f);
            float o7 = fmaxf(ac[7] + s3.y * sl + bc.w, 0.f);
            uint4 ov;
            ov.x = pk2(o0, o1);
            ov.y = pk2(o2, o3);
            ov.z = pk2(o4, o5);
            ov.w = pk2(o6, o7);
            unsigned cb = lb ^ (((unsigned)nl & 7u) << 4);   // XOR-swizzle (G4)
            *reinterpret_cast<uint4*>((char*)As + nl * 256 + cb) = ov;
        }
    }

    // ---- W2 fragments to registers (16KB, L2-hot; live only through phase 2) ----
    bf16x8 bfr[4][3];
    #pragma unroll
    for (int ks = 0; ks < 4; ++ks)
        #pragma unroll
        for (int ni = 0; ni < 3; ++ni)
            bfr[ks][ni] = *(const bf16x8*)(W2t + (size_t)(ni * 16 + l16) * NH + ks * 32 + quad * 8);

    __syncthreads();

    // ---- phase 2: 128x48x128 MFMA from LDS, 8 waves x 16 rows ----
    f32x4 acc2[3] = {};
    #pragma unroll
    for (int ks = 0; ks < 4; ++ks) {
        int row = wave * 16 + l16;
        unsigned cb = ((unsigned)(ks * 64 + quad * 16)) ^ (((unsigned)row & 7u) << 4);
        bf16x8 afr = *(const bf16x8*)((const char*)As + row * 256 + cb);
        #pragma unroll
        for (int ni = 0; ni < 3; ++ni)
            acc2[ni] = __builtin_amdgcn_mfma_f32_16x16x32_bf16(
                afr, bfr[ks][ni], acc2[ni], 0, 0, 0);
    }

    #pragma unroll
    for (int v = 0; v < 4; ++v) {
        int r = m0 + wave * 16 + quad * 4 + v;
        if (r < NN) {
            #pragma unroll
            for (int ni = 0; ni < 3; ++ni) {
                int c = ni * 16 + l16;
                H2p[(size_t)r * NC2 + c] = __float2bfloat16(acc2[ni][v]);
            }
        }
    }
}

// ---------------- layer-2 gather (group-per-node) + self + bias + log_softmax ----------------
__global__ void agg2_lsm(const int* __restrict__ offsets, const int2* __restrict__ erec,
                         const float* __restrict__ dinv, const __hip_bfloat16* __restrict__ H2p,
                         const float* __restrict__ b2, float* __restrict__ out) {
    int node = (blockIdx.x * blockDim.x + threadIdx.x) >> 4;
    if (node >= NN) return;
    int l16 = threadIdx.x & 15;
    const char* Hb = (const char*)H2p;
    const bool lv = (l16 < 12);      // 12 lanes x 8B = 96B = 48 bf16 row
    const unsigned lo = (unsigned)(l16 * 8);
    const uint2 zz = make_uint2(0u, 0u);
    float a0 = 0.f, a1 = 0.f, a2 = 0.f, a3 = 0.f;
    int beg = offsets[node], end = offsets[node + 1];
    for (int p = beg; p < end; p += 4) {
        int2 e0 = erec[p];
        int2 e1 = (p + 1 < end) ? erec[p + 1] : make_int2(0, 0);
        int2 e2 = (p + 2 < end) ? erec[p + 2] : make_int2(0, 0);
        int2 e3 = (p + 3 < end) ? erec[p + 3] : make_int2(0, 0);
        uint2 h0 = lv ? *(const uint2*)(Hb + ((unsigned)e0.x & 0x1FFFFu) * 96u + lo) : zz;
        uint2 h1 = lv ? *(const uint2*)(Hb + ((unsigned)e1.x & 0x1FFFFu) * 96u + lo) : zz;
        uint2 h2 = lv ? *(const uint2*)(Hb + ((unsigned)e2.x & 0x1FFFFu) * 96u + lo) : zz;
        uint2 h3 = lv ? *(const uint2*)(Hb + ((unsigned)e3.x & 0x1FFFFu) * 96u + lo) : zz;
        float w0 = __int_as_float(e0.y), w1 = __int_as_float(e1.y);
        float w2 = __int_as_float(e2.y), w3 = __int_as_float(e3.y);
        #define ACC4(hv, ww) { \
            float2 q0 = cvt2(hv.x), q1 = cvt2(hv.y); \
            a0 += q0.x * (ww); a1 += q0.y * (ww); \
            a2 += q1.x * (ww); a3 += q1.y * (ww); }
        ACC4(h0, w0) ACC4(h1, w1) ACC4(h2, w2) ACC4(h3, w3)
        #undef ACC4
    }
    float v0, v1, v2, v3;
    bool valid = (l16 < 10);   // classes l16*4..l16*4+3 < 40
    if (valid) {
        float di = dinv[node];
        float sl = di * di;
        uint2 hs = *(const uint2*)(Hb + ((unsigned)node & 0x1FFFFu) * 96u + lo);
        float2 s0 = cvt2(hs.x), s1 = cvt2(hs.y);
        float4 bb = *reinterpret_cast<const float4*>(b2 + l16 * 4);
        v0 = a0 + s0.x * sl + bb.x;
        v1 = a1 + s0.y * sl + bb.y;
        v2 = a2 + s1.x * sl + bb.z;
        v3 = a3 + s1.y * sl + bb.w;
    } else {
        v0 = v1 = v2 = v3 = -INFINITY;
    }
    float m = fmaxf(fmaxf(v0, v1), fmaxf(v2, v3));
    #pragma unroll
    for (int off = 8; off; off >>= 1) m = fmaxf(m, __shfl_xor(m, off, 64));
    float ex = expf(v0 - m) + expf(v1 - m) + expf(v2 - m) + expf(v3 - m);
    #pragma unroll
    for (int off = 8; off; off >>= 1) ex += __shfl_xor(ex, off, 64);
    float ls = logf(ex);
    if (valid) {
        float4 o;
        o.x = v0 - m - ls; o.y = v1 - m - ls;
        o.z = v2 - m - ls; o.w = v3 - m - ls;
        *reinterpret_cast<float4*>(out + (size_t)node * NC + l16 * 4) = o;
    }
}

extern "C" void kernel_launch(void* const* d_in, const int* in_sizes, int n_in,
                              void* d_out, int out_size, void* d_ws, size_t ws_size,
                              hipStream_t stream) {
    const float* x  = (const float*)d_in[0];
    const int*   ei = (const int*)d_in[1];
    const float* W1 = (const float*)d_in[2];
    const float* b1 = (const float*)d_in[3];
    const float* W2 = (const float*)d_in[4];
    const float* b2 = (const float*)d_in[5];
    float* out = (float*)d_out;

    int*   counts     = (int*)d_ws;
    int*   offsets    = counts + OFF_OFFSETS;
    int*   bin_cursor = counts + OFF_CURSOR;
    float* dinv       = (float*)(counts + OFF_DINV);
    int2*  erec       = (int2*)(counts + OFF_EREC);
    __hip_bfloat16* H     = (__hip_bfloat16*)(counts + OFF_H);
    __hip_bfloat16* W1t   = (__hip_bfloat16*)(counts + OFF_W1T);
    __hip_bfloat16* W2t   = (__hip_bfloat16*)(counts + OFF_W2T);
    int*            ebin  = counts + OFF_HAGG;                    // dead after passB
    __hip_bfloat16* H2p   = (__hip_bfloat16*)(counts + OFF_HAGG); // packed [NN][48] bf16, reuses ebin

    int* blocksums = counts + OFF_H;             // scan scratch (before gemm1 writes H)

    // 1. CSR build: count + W1t/W2t prep, then scan (offsets, dinv, bin cursor bases)
    (void)hipMemsetAsync(counts, 0, NN * sizeof(int), stream);
    count_prep<<<(NE + 255) / 256, 256, 0, stream>>>(ei + NE, counts, W1, W1t, W2, W2t);
    scan_phase1<<<SCAN_NB, SCAN_TILE, 0, stream>>>(counts, blocksums);
    scan_phase3<<<SCAN_NB, SCAN_TILE, 0, stream>>>(counts, blocksums, offsets, bin_cursor, dinv);

    // 2. FUSED+INTERLEAVED: gemm1 (MFMA, 512 thr, dbuf) + pass A coarse binning
    gemm1_passA<<<GEMM1_NB + NB_A, 512, 0, stream>>>(ei, bin_cursor, ebin, x, W1t, H);

    // 2b. pass B: within-bin sort -> erec (one block per bin, L2-local writes)
    passB<<<NBINS, 256, 0, stream>>>(offsets, ebin, dinv, erec);

    // 3. FUSED layer-1 gather + layer-2 GEMM -> H2p (512 thr, no Haggb round-trip)
    agg1_gemm2<<<(NN + 127) / 128, 512, 0, stream>>>(offsets, erec, dinv, H, b1, W2t, H2p);

    // 4. layer-2 gather + self + bias + log_softmax -> out
    {
        long long threads = (long long)NN * 16;
        agg2_lsm<<<(unsigned)((threads + 255) / 256), 256, 0, stream>>>(
            offsets, erec, dinv, H2p, b2, out);
    }
}

// Round 4
// 406.608 us; speedup vs baseline: 1.0416x; 1.0109x over previous
//
#include <hip/hip_runtime.h>
#include <hip/hip_bf16.h>
#include <math.h>

#define NN 100000      // nodes
#define NE 1600000     // edges
#define NF 256         // input features
#define NH 128         // hidden
#define NC 40          // classes
#define NCP 64         // padded classes for W2t (rows >=40 zero)
#define NC2 48         // packed H2p row width (classes 40..47 are zero)

// Workspace layout (4-byte units):
//   counts     [0,       100032)
//   offsets    [100032,  200128)   (NN+1 used)
//   bin_cursor [200128,  300160)   (NBINS used)
//   dinv       [300160,  400192)
//   erec       [400192,  3600192)  (NE int2)
//   H          [3600192, 10000192) (bf16 NN*NH; scan scratch early)
//   w1t        [10000192,10016576) (bf16 [128][256])
//   w2t        [10016576,10020672) (bf16 [64][128], rows >=40 zero)
//   ebin/H2p   [16400192,29200192) (ebin NE ints during passA/B; H2p bf16 [NN][48] after)
#define OFF_OFFSETS 100032
#define OFF_CURSOR  200128
#define OFF_DINV    300160
#define OFF_EREC    400192
#define OFF_H       3600192
#define OFF_W1T     10000192
#define OFF_W2T     10016576
#define OFF_HAGG    16400192

#define SCAN_TILE 1024
#define SCAN_NB   ((NN + SCAN_TILE - 1) / SCAN_TILE)   // 98

#define GEMM1_NB  ((NN + 127) / 128)    // 782
#define NBINS     ((NN + 255) / 256)    // 391
#define CHUNK_A   4096
#define NB_A      ((NE + CHUNK_A - 1) / CHUNK_A)       // 391 (= GEMM1_NB/2)

using f32x4  = __attribute__((ext_vector_type(4))) float;
using bf16x8 = __attribute__((ext_vector_type(8))) short;

// decode packed pair of bf16 (lo, hi) to fp32x2 — exact, pure bit ops
__device__ inline float2 cvt2(unsigned u) {
    float2 f;
    f.x = __uint_as_float(u << 16);
    f.y = __uint_as_float(u & 0xffff0000u);
    return f;
}

__device__ inline short bfbits(float f) {
    __hip_bfloat16 h = __float2bfloat16(f);
    return *reinterpret_cast<short*>(&h);
}

__device__ inline unsigned pk2(float lo, float hi) {
    return (unsigned)(unsigned short)bfbits(lo) | ((unsigned)(unsigned short)bfbits(hi) << 16);
}

// ---------------- count + W1t/W2t prep (fused, independent work) ----------------
__global__ void count_prep(const int* __restrict__ dst, int* __restrict__ count,
                           const float* __restrict__ W1, __hip_bfloat16* __restrict__ W1t,
                           const float* __restrict__ W2, __hip_bfloat16* __restrict__ W2t) {
    int t = blockIdx.x * blockDim.x + threadIdx.x;
    if (t < NE) atomicAdd(&count[dst[t]], 1);
    if (t < NH * NF) {
        int n = t >> 8;
        int k = t & (NF - 1);
        W1t[t] = __float2bfloat16(W1[(size_t)k * NH + n]);
    }
    if (t < NCP * NH) {
        int n = t >> 7;
        int k = t & (NH - 1);
        W2t[t] = __float2bfloat16((n < NC) ? W2[(size_t)k * NC + n] : 0.f);
    }
}

// ---- hierarchical scan (phase2 fused into phase3) ----
__global__ void scan_phase1(const int* __restrict__ count, int* __restrict__ blocksums) {
    int b = blockIdx.x, t = threadIdx.x;
    int i = b * SCAN_TILE + t;
    int v = (i < NN) ? count[i] : 0;
    #pragma unroll
    for (int off = 32; off; off >>= 1) v += __shfl_xor(v, off, 64);
    __shared__ int ws[16];
    int lane = t & 63, wave = t >> 6;
    if (lane == 0) ws[wave] = v;
    __syncthreads();
    if (t == 0) {
        int s = 0;
        #pragma unroll
        for (int w = 0; w < SCAN_TILE / 64; ++w) s += ws[w];
        blocksums[b] = s;
    }
}

// phase 3: block prefix (from blocksums) + offsets + dinv + per-bin cursor bases
__global__ void scan_phase3(const int* __restrict__ count, const int* __restrict__ blocksums,
                            int* __restrict__ offsets, int* __restrict__ bin_cursor,
                            float* __restrict__ dinv) {
    int b = blockIdx.x, t = threadIdx.x;
    int lane = t & 63, wave = t >> 6;

    // fused phase2: sum blocksums[0..b-1] using first 2 waves (SCAN_NB=98 <= 128)
    __shared__ int bsum2[2];
    if (t < 128) {
        int u = (t < b) ? blocksums[t] : 0;   // t < b <= 97 < SCAN_NB, in bounds
        #pragma unroll
        for (int off = 32; off; off >>= 1) u += __shfl_xor(u, off, 64);
        if (lane == 0) bsum2[wave] = u;
    }

    int i = b * SCAN_TILE + t;
    int v = (i < NN) ? count[i] : 0;
    int s = v;
    #pragma unroll
    for (int off = 1; off < 64; off <<= 1) {
        int u = __shfl_up(s, off, 64);
        if (lane >= off) s += u;
    }
    __shared__ int wsum[16];
    if (lane == 63) wsum[wave] = s;
    __syncthreads();
    if (t < 16) {
        int x = wsum[t];
        #pragma unroll
        for (int off = 1; off < 16; off <<= 1) {
            int u = __shfl_up(x, off, 64);
            if (t >= off) x += u;
        }
        wsum[t] = x;
    }
    __syncthreads();
    int bpref = bsum2[0] + bsum2[1];
    int excl = (s - v) + (wave ? wsum[wave - 1] : 0) + bpref;
    if (i < NN) {
        offsets[i] = excl;
        dinv[i]    = rsqrtf((float)v + 1.0f);   // +1 self loop
        if ((i & 255) == 0) bin_cursor[i >> 8] = excl;
        if (i == NN - 1) offsets[NN] = excl + v;
    }
}

// ---------------- FUSED + INTERLEAVED: layer-1 MFMA GEMM (1024 thr, dbuf) + pass A ----------------
// Block pattern (3k blocks): b%3==1 -> passA chunk b/3; else gemm tile 2*(b/3)+(b%3==2)
// 1024 threads/block: 16 waves per 128x128 tile; 2 blocks/CU (thread-capped) = 32 waves/CU.
__global__ __launch_bounds__(1024, 2) void gemm1_passA(
        const int* __restrict__ ei, int* __restrict__ bin_cursor,
        int* __restrict__ ebin,
        const float* __restrict__ X, const __hip_bfloat16* __restrict__ W1t,
        __hip_bfloat16* __restrict__ H) {
    __shared__ __align__(16) int smem[12288];   // 48 KB: gemm As dbuf(32K)+Bs dbuf(16K) OR passA hist/rbase

    const int bi = blockIdx.x / 3;
    const int br = blockIdx.x % 3;

    if (br == 1) {
        // ---- pass A: partition 4096 edges into 256-node bins, run-coalesced writes ----
        int* hist  = smem;
        int* rbase = smem + NBINS;
        int e0 = bi * CHUNK_A;
        int e1 = e0 + CHUNK_A; if (e1 > NE) e1 = NE;
        for (int j = threadIdx.x; j < NBINS; j += 1024) hist[j] = 0;
        __syncthreads();
        for (int p = e0 + threadIdx.x; p < e1; p += 1024)
            atomicAdd(&hist[ei[NE + p] >> 8], 1);
        __syncthreads();
        for (int j = threadIdx.x; j < NBINS; j += 1024) {
            int c = hist[j];
            rbase[j] = c ? atomicAdd(&bin_cursor[j], c) : 0;
        }
        __syncthreads();
        for (int p = e0 + threadIdx.x; p < e1; p += 1024) {
            int s = ei[p];
            int d = ei[NE + p];
            int bb = d >> 8;
            int pos = atomicAdd(&rbase[bb], 1);
            ebin[pos] = s | ((d & 255) << 17);
        }
        return;
    }

    // ---- gemm1 path: H = bf16(x @ W1), 128x128 tile, 16 waves, dbuf K-loop ----
    float* As = (float*)smem;           // 2 x [128][32] fp32 (buf stride 4096 floats)
    short* Bs = (short*)(smem + 8192);  // 2 x [128][32] bf16 (buf stride 4096 shorts)

    const int tid  = threadIdx.x;
    const int wave = tid >> 6;          // 0..15
    const int lane = tid & 63;
    const int quad = lane >> 4;
    const int l16  = lane & 15;
    const int wy = wave >> 1, wx = wave & 1;    // wy 0..7 (16-row block), wx 0..1 (64-col block)
    const int m0 = (bi * 2 + (br == 2 ? 1 : 0)) * 128;

    f32x4 acc[4] = {};

    auto stage = [&](int d, int kk) {
        // As: 1024 x 16B chunks, exactly 1 per thread
        {
            int row = tid >> 3, cc = tid & 7;
            int gr  = m0 + row; if (gr > NN - 1) gr = NN - 1;
            const float* gp = X + (size_t)gr * NF + kk + cc * 4;
            __builtin_amdgcn_global_load_lds(
                (const __attribute__((address_space(1))) void*)gp,
                (__attribute__((address_space(3))) void*)&As[d * 4096 + wave * 256],
                16, 0, 0);
        }
        // Bs: 512 x 16B chunks, waves 0..7 (wave-uniform predicate)
        if (wave < 8) {
            int n = tid >> 2, cc = tid & 3;
            const __hip_bfloat16* gp = W1t + (size_t)n * NF + kk + cc * 8;
            __builtin_amdgcn_global_load_lds(
                (const __attribute__((address_space(1))) void*)gp,
                (__attribute__((address_space(3))) void*)&Bs[d * 4096 + wave * 512],
                16, 0, 0);
        }
    };

    // prologue: fill buffer 0, drain, barrier
    stage(0, 0);
    __syncthreads();

    int cur = 0;
    #pragma unroll
    for (int k0 = 0; k0 < NF; k0 += 32) {
        if (k0 + 32 < NF) stage(cur ^ 1, k0 + 32);   // prefetch next tile (in flight during MFMA)

        bf16x8 a_frag, b_frag[4];
        {
            const float* ap = &As[cur * 4096 + (wy * 16 + l16) * 32 + quad * 8];
            f32x4 a0 = *(const f32x4*)ap;
            f32x4 a1 = *(const f32x4*)(ap + 4);
            bf16x8 af;
            af[0] = bfbits(a0.x); af[1] = bfbits(a0.y);
            af[2] = bfbits(a0.z); af[3] = bfbits(a0.w);
            af[4] = bfbits(a1.x); af[5] = bfbits(a1.y);
            af[6] = bfbits(a1.z); af[7] = bfbits(a1.w);
            a_frag = af;
        }
        #pragma unroll
        for (int ni = 0; ni < 4; ++ni) {
            const short* bp = &Bs[cur * 4096 + (wx * 64 + ni * 16 + l16) * 32 + quad * 8];
            b_frag[ni] = *(const bf16x8*)bp;
        }
        #pragma unroll
        for (int ni = 0; ni < 4; ++ni)
            acc[ni] = __builtin_amdgcn_mfma_f32_16x16x32_bf16(
                a_frag, b_frag[ni], acc[ni], 0, 0, 0);

        __syncthreads();   // drains this iter's prefetch (vmcnt 0) + protects buffer swap
        cur ^= 1;
    }

    #pragma unroll
    for (int v = 0; v < 4; ++v) {
        int r = m0 + wy * 16 + quad * 4 + v;
        if (r < NN) {
            #pragma unroll
            for (int ni = 0; ni < 4; ++ni) {
                int c = wx * 64 + ni * 16 + l16;
                H[(size_t)r * NH + c] = __float2bfloat16(acc[ni][v]);
            }
        }
    }
}

// ---------------- pass B: within-bin counting sort -> erec (L2-local writes) ----------------
__global__ __launch_bounds__(256) void passB(const int* __restrict__ offsets,
                                             const int* __restrict__ ebin,
                                             const float* __restrict__ dinv,
                                             int2* __restrict__ erec) {
    int b = blockIdx.x;
    int n0 = b << 8;
    int nodes = NN - n0; if (nodes > 256) nodes = 256;
    __shared__ int cur[256];
    __shared__ float dls[256];
    if (threadIdx.x < nodes) {
        cur[threadIdx.x] = offsets[n0 + threadIdx.x];
        dls[threadIdx.x] = dinv[n0 + threadIdx.x];
    }
    __syncthreads();
    int binstart = offsets[n0];
    int binend   = offsets[n0 + nodes];
    for (int p = binstart + threadIdx.x; p < binend; p += 256) {
        int e  = ebin[p];
        int s  = e & 0x1FFFF;
        int dl = e >> 17;
        int pos = atomicAdd(&cur[dl], 1);
        float w = dinv[s] * dls[dl];
        erec[pos] = make_int2(s, __float_as_int(w));
    }
}

// ---------------- FUSED: layer-1 gather (group-per-node) + layer-2 GEMM from LDS ----------------
// 1024 threads/block: 64 gather groups x 2 nodes; MFMA phase waves 0..7 (waves 8..15 retire).
// 32KB LDS, thread-capped 2 blocks/CU = 32 waves/CU (100% ceiling).
__global__ __launch_bounds__(1024, 2) void agg1_gemm2(
        const int* __restrict__ offsets, const int2* __restrict__ erec,
        const float* __restrict__ dinv, const __hip_bfloat16* __restrict__ H,
        const float* __restrict__ b1, const __hip_bfloat16* __restrict__ W2t,
        __hip_bfloat16* __restrict__ H2p) {
    __shared__ __align__(16) short As[128 * 128];   // 32 KB swizzled Hagg tile
    const int tid  = threadIdx.x;
    const int wave = tid >> 6;      // 0..15
    const int lane = tid & 63;
    const int quad = lane >> 4;
    const int l16  = lane & 15;
    const int grp  = tid >> 4;      // 0..63 gather group
    const int m0   = blockIdx.x * 128;
    const char* Hb = (const char*)H;
    const unsigned lb = (unsigned)(l16 << 4);

    // ---- phase 1: each 16-lane group owns one node, 4 gather loads in flight ----
    #pragma unroll 1
    for (int rd = 0; rd < 2; ++rd) {
        int nl = rd * 64 + grp;
        int node = m0 + nl;
        if (node < NN) {
            int beg = offsets[node], end = offsets[node + 1];
            float ac[8] = {};
            for (int p = beg; p < end; p += 4) {
                int2 e0 = erec[p];
                int2 e1 = (p + 1 < end) ? erec[p + 1] : make_int2(0, 0);
                int2 e2 = (p + 2 < end) ? erec[p + 2] : make_int2(0, 0);
                int2 e3 = (p + 3 < end) ? erec[p + 3] : make_int2(0, 0);
                uint4 h0 = *(const uint4*)(Hb + (((unsigned)e0.x) << 8) + lb);
                uint4 h1 = *(const uint4*)(Hb + (((unsigned)e1.x) << 8) + lb);
                uint4 h2 = *(const uint4*)(Hb + (((unsigned)e2.x) << 8) + lb);
                uint4 h3 = *(const uint4*)(Hb + (((unsigned)e3.x) << 8) + lb);
                float w0 = __int_as_float(e0.y), w1 = __int_as_float(e1.y);
                float w2 = __int_as_float(e2.y), w3 = __int_as_float(e3.y);
                #define ACC8(hv, ww) { \
                    float2 q0 = cvt2(hv.x), q1 = cvt2(hv.y), q2 = cvt2(hv.z), q3 = cvt2(hv.w); \
                    ac[0] += q0.x * (ww); ac[1] += q0.y * (ww); \
                    ac[2] += q1.x * (ww); ac[3] += q1.y * (ww); \
                    ac[4] += q2.x * (ww); ac[5] += q2.y * (ww); \
                    ac[6] += q3.x * (ww); ac[7] += q3.y * (ww); }
                ACC8(h0, w0) ACC8(h1, w1) ACC8(h2, w2) ACC8(h3, w3)
                #undef ACC8
            }
            // self loop + bias + relu -> bf16 row in LDS
            float di = dinv[node];
            float sl = di * di;
            uint4 hs = *(const uint4*)(Hb + (((unsigned)node) << 8) + lb);
            float2 s0 = cvt2(hs.x), s1 = cvt2(hs.y), s2 = cvt2(hs.z), s3 = cvt2(hs.w);
            const float4* bb = reinterpret_cast<const float4*>(b1 + l16 * 8);
            float4 ba = bb[0], bc = bb[1];
            float o0 = fmaxf(ac[0] + s0.x * sl + ba.x, 0.f);
            float o1 = fmaxf(ac[1] + s0.y * sl + ba.y, 0.f);
            float o2 = fmaxf(ac[2] + s1.x * sl + ba.z, 0.f);
            float o3 = fmaxf(ac[3] + s1.y * sl + ba.w, 0.f);
            float o4 = fmaxf(ac[4] + s2.x * sl + bc.x, 0.f);
            float o5 = fmaxf(ac[5] + s2.y * sl + bc.y, 0.f);
            float o6 = fmaxf(ac[6] + s3.x * sl + bc.z, 0.f);
            float o7 = fmaxf(ac[7] + s3.y * sl + bc.w, 0.f);
            uint4 ov;
            ov.x = pk2(o0, o1);
            ov.y = pk2(o2, o3);
            ov.z = pk2(o4, o5);
            ov.w = pk2(o6, o7);
            unsigned cb = lb ^ (((unsigned)nl & 7u) << 4);   // XOR-swizzle (G4)
            *reinterpret_cast<uint4*>((char*)As + nl * 256 + cb) = ov;
        }
    }

    // ---- W2 fragments to registers (16KB, L2-hot; only MFMA waves need them) ----
    bf16x8 bfr[4][3];
    if (wave < 8) {
        #pragma unroll
        for (int ks = 0; ks < 4; ++ks)
            #pragma unroll
            for (int ni = 0; ni < 3; ++ni)
                bfr[ks][ni] = *(const bf16x8*)(W2t + (size_t)(ni * 16 + l16) * NH + ks * 32 + quad * 8);
    }

    __syncthreads();
    if (wave >= 8) return;   // no further barriers; upper waves retire

    // ---- phase 2: 128x48x128 MFMA from LDS, waves 0..7 x 16 rows ----
    f32x4 acc2[3] = {};
    #pragma unroll
    for (int ks = 0; ks < 4; ++ks) {
        int row = wave * 16 + l16;
        unsigned cb = ((unsigned)(ks * 64 + quad * 16)) ^ (((unsigned)row & 7u) << 4);
        bf16x8 afr = *(const bf16x8*)((const char*)As + row * 256 + cb);
        #pragma unroll
        for (int ni = 0; ni < 3; ++ni)
            acc2[ni] = __builtin_amdgcn_mfma_f32_16x16x32_bf16(
                afr, bfr[ks][ni], acc2[ni], 0, 0, 0);
    }

    #pragma unroll
    for (int v = 0; v < 4; ++v) {
        int r = m0 + wave * 16 + quad * 4 + v;
        if (r < NN) {
            #pragma unroll
            for (int ni = 0; ni < 3; ++ni) {
                int c = ni * 16 + l16;
                H2p[(size_t)r * NC2 + c] = __float2bfloat16(acc2[ni][v]);
            }
        }
    }
}

// ---------------- layer-2 gather (group-per-node) + self + bias + log_softmax ----------------
__global__ void agg2_lsm(const int* __restrict__ offsets, const int2* __restrict__ erec,
                         const float* __restrict__ dinv, const __hip_bfloat16* __restrict__ H2p,
                         const float* __restrict__ b2, float* __restrict__ out) {
    int node = (blockIdx.x * blockDim.x + threadIdx.x) >> 4;
    if (node >= NN) return;
    int l16 = threadIdx.x & 15;
    const char* Hb = (const char*)H2p;
    const bool lv = (l16 < 12);      // 12 lanes x 8B = 96B = 48 bf16 row
    const unsigned lo = (unsigned)(l16 * 8);
    const uint2 zz = make_uint2(0u, 0u);
    float a0 = 0.f, a1 = 0.f, a2 = 0.f, a3 = 0.f;
    int beg = offsets[node], end = offsets[node + 1];
    for (int p = beg; p < end; p += 4) {
        int2 e0 = erec[p];
        int2 e1 = (p + 1 < end) ? erec[p + 1] : make_int2(0, 0);
        int2 e2 = (p + 2 < end) ? erec[p + 2] : make_int2(0, 0);
        int2 e3 = (p + 3 < end) ? erec[p + 3] : make_int2(0, 0);
        uint2 h0 = lv ? *(const uint2*)(Hb + ((unsigned)e0.x & 0x1FFFFu) * 96u + lo) : zz;
        uint2 h1 = lv ? *(const uint2*)(Hb + ((unsigned)e1.x & 0x1FFFFu) * 96u + lo) : zz;
        uint2 h2 = lv ? *(const uint2*)(Hb + ((unsigned)e2.x & 0x1FFFFu) * 96u + lo) : zz;
        uint2 h3 = lv ? *(const uint2*)(Hb + ((unsigned)e3.x & 0x1FFFFu) * 96u + lo) : zz;
        float w0 = __int_as_float(e0.y), w1 = __int_as_float(e1.y);
        float w2 = __int_as_float(e2.y), w3 = __int_as_float(e3.y);
        #define ACC4(hv, ww) { \
            float2 q0 = cvt2(hv.x), q1 = cvt2(hv.y); \
            a0 += q0.x * (ww); a1 += q0.y * (ww); \
            a2 += q1.x * (ww); a3 += q1.y * (ww); }
        ACC4(h0, w0) ACC4(h1, w1) ACC4(h2, w2) ACC4(h3, w3)
        #undef ACC4
    }
    float v0, v1, v2, v3;
    bool valid = (l16 < 10);   // classes l16*4..l16*4+3 < 40
    if (valid) {
        float di = dinv[node];
        float sl = di * di;
        uint2 hs = *(const uint2*)(Hb + ((unsigned)node & 0x1FFFFu) * 96u + lo);
        float2 s0 = cvt2(hs.x), s1 = cvt2(hs.y);
        float4 bb = *reinterpret_cast<const float4*>(b2 + l16 * 4);
        v0 = a0 + s0.x * sl + bb.x;
        v1 = a1 + s0.y * sl + bb.y;
        v2 = a2 + s1.x * sl + bb.z;
        v3 = a3 + s1.y * sl + bb.w;
    } else {
        v0 = v1 = v2 = v3 = -INFINITY;
    }
    float m = fmaxf(fmaxf(v0, v1), fmaxf(v2, v3));
    #pragma unroll
    for (int off = 8; off; off >>= 1) m = fmaxf(m, __shfl_xor(m, off, 64));
    float ex = expf(v0 - m) + expf(v1 - m) + expf(v2 - m) + expf(v3 - m);
    #pragma unroll
    for (int off = 8; off; off >>= 1) ex += __shfl_xor(ex, off, 64);
    float ls = logf(ex);
    if (valid) {
        float4 o;
        o.x = v0 - m - ls; o.y = v1 - m - ls;
        o.z = v2 - m - ls; o.w = v3 - m - ls;
        *reinterpret_cast<float4*>(out + (size_t)node * NC + l16 * 4) = o;
    }
}

extern "C" void kernel_launch(void* const* d_in, const int* in_sizes, int n_in,
                              void* d_out, int out_size, void* d_ws, size_t ws_size,
                              hipStream_t stream) {
    const float* x  = (const float*)d_in[0];
    const int*   ei = (const int*)d_in[1];
    const float* W1 = (const float*)d_in[2];
    const float* b1 = (const float*)d_in[3];
    const float* W2 = (const float*)d_in[4];
    const float* b2 = (const float*)d_in[5];
    float* out = (float*)d_out;

    int*   counts     = (int*)d_ws;
    int*   offsets    = counts + OFF_OFFSETS;
    int*   bin_cursor = counts + OFF_CURSOR;
    float* dinv       = (float*)(counts + OFF_DINV);
    int2*  erec       = (int2*)(counts + OFF_EREC);
    __hip_bfloat16* H     = (__hip_bfloat16*)(counts + OFF_H);
    __hip_bfloat16* W1t   = (__hip_bfloat16*)(counts + OFF_W1T);
    __hip_bfloat16* W2t   = (__hip_bfloat16*)(counts + OFF_W2T);
    int*            ebin  = counts + OFF_HAGG;                    // dead after passB
    __hip_bfloat16* H2p   = (__hip_bfloat16*)(counts + OFF_HAGG); // packed [NN][48] bf16, reuses ebin

    int* blocksums = counts + OFF_H;             // scan scratch (before gemm1 writes H)

    // 1. CSR build: count + W1t/W2t prep, then scan (offsets, dinv, bin cursor bases)
    (void)hipMemsetAsync(counts, 0, NN * sizeof(int), stream);
    count_prep<<<(NE + 255) / 256, 256, 0, stream>>>(ei + NE, counts, W1, W1t, W2, W2t);
    scan_phase1<<<SCAN_NB, SCAN_TILE, 0, stream>>>(counts, blocksums);
    scan_phase3<<<SCAN_NB, SCAN_TILE, 0, stream>>>(counts, blocksums, offsets, bin_cursor, dinv);

    // 2. FUSED+INTERLEAVED: gemm1 (MFMA, 1024 thr, dbuf) + pass A coarse binning
    gemm1_passA<<<GEMM1_NB + NB_A, 1024, 0, stream>>>(ei, bin_cursor, ebin, x, W1t, H);

    // 2b. pass B: within-bin sort -> erec (one block per bin, L2-local writes)
    passB<<<NBINS, 256, 0, stream>>>(offsets, ebin, dinv, erec);

    // 3. FUSED layer-1 gather + layer-2 GEMM -> H2p (1024 thr, no Haggb round-trip)
    agg1_gemm2<<<(NN + 127) / 128, 1024, 0, stream>>>(offsets, erec, dinv, H, b1, W2t, H2p);

    // 4. layer-2 gather + self + bias + log_softmax -> out
    {
        long long threads = (long long)NN * 16;
        agg2_lsm<<<(unsigned)((threads + 255) / 256), 256, 0, stream>>>(
            offsets, erec, dinv, H2p, b2, out);
    }
}

// Round 5
// 321.211 us; speedup vs baseline: 1.3185x; 1.2659x over previous
//
#include <hip/hip_runtime.h>
#include <hip/hip_bf16.h>
#include <math.h>

#define NN 100000      // nodes
#define NE 1600000     // edges
#define NF 256         // input features
#define NH 128         // hidden
#define NC 40          // classes
#define NCP 64         // padded classes for W2t (rows >=40 zero)
#define NC2 48         // packed H2p row width (classes 40..47 are zero)

#define NBINS     ((NN + 255) / 256)    // 391
#define BIN_CAP   5120                  // mean bin load 4096, sd~64 -> 16-sigma safe
#define CHUNK_A   4096
#define NB_A      ((NE + CHUNK_A - 1) / CHUNK_A)       // 391
#define GEMM1_NB  ((NN + 127) / 128)    // 782

// Workspace layout (4-byte units), max usage ~22.9M units (91.6MB):
//   offr       [0,       200000)   int2 per node {beg,end} into erec4
//   bin_cursor [200128,  200519)
//   dinv       [300160,  400160)
//   H          [3600192, 10000192) (bf16 NN*NH)
//   w1t        [10000192,10016576) (bf16 [128][256])
//   w2t        [10016576,10020672) (bf16 [64][128], rows >=40 zero)
//   ebin       [16400192,18402112) (NBINS*BIN_CAP ints, dead after buildK2)
//   erec4      [18402112,20404032) (NBINS*BIN_CAP ints: src per edge)
//   H2p        [20404032,22804032) (bf16 [NN][48])
#define OFF_CURSOR  200128
#define OFF_DINV    300160
#define OFF_H       3600192
#define OFF_W1T     10000192
#define OFF_W2T     10016576
#define OFF_EBIN    16400192
#define OFF_EREC4   18402112
#define OFF_H2P     20404032

using f32x4  = __attribute__((ext_vector_type(4))) float;
using bf16x8 = __attribute__((ext_vector_type(8))) short;

// decode packed pair of bf16 (lo, hi) to fp32x2 — exact, pure bit ops
__device__ inline float2 cvt2(unsigned u) {
    float2 f;
    f.x = __uint_as_float(u << 16);
    f.y = __uint_as_float(u & 0xffff0000u);
    return f;
}

__device__ inline short bfbits(float f) {
    __hip_bfloat16 h = __float2bfloat16(f);
    return *reinterpret_cast<short*>(&h);
}

__device__ inline unsigned pk2(float lo, float hi) {
    return (unsigned)(unsigned short)bfbits(lo) | ((unsigned)(unsigned short)bfbits(hi) << 16);
}

// ---------------- K0: bin cursor bases + W1t/W2t prep ----------------
__global__ void initk(int* __restrict__ bin_cursor,
                      const float* __restrict__ W1, __hip_bfloat16* __restrict__ W1t,
                      const float* __restrict__ W2, __hip_bfloat16* __restrict__ W2t) {
    int t = blockIdx.x * blockDim.x + threadIdx.x;
    if (t < NBINS) bin_cursor[t] = t * BIN_CAP;
    if (t < NH * NF) {
        int n = t >> 8;
        int k = t & (NF - 1);
        W1t[t] = __float2bfloat16(W1[(size_t)k * NH + n]);
    }
    if (t < NCP * NH) {
        int n = t >> 7;
        int k = t & (NH - 1);
        W2t[t] = __float2bfloat16((n < NC) ? W2[(size_t)k * NC + n] : 0.f);
    }
}

// ---------------- K1: FUSED layer-1 MFMA GEMM (1024 thr, dbuf) + pass A binning ----------------
// Block pattern (3k blocks): b%3==1 -> passA chunk b/3; else gemm tile 2*(b/3)+(b%3==2)
__global__ __launch_bounds__(1024, 2) void gemm1_passA(
        const int* __restrict__ ei, int* __restrict__ bin_cursor,
        int* __restrict__ ebin,
        const float* __restrict__ X, const __hip_bfloat16* __restrict__ W1t,
        __hip_bfloat16* __restrict__ H) {
    __shared__ __align__(16) int smem[12288];   // 48 KB: gemm As dbuf(32K)+Bs dbuf(16K) OR passA hist/rbase

    const int bi = blockIdx.x / 3;
    const int br = blockIdx.x % 3;

    if (br == 1) {
        // ---- pass A: partition 4096 edges into 256-node bins, run-coalesced writes ----
        int* hist  = smem;
        int* rbase = smem + NBINS;
        int e0 = bi * CHUNK_A;
        int e1 = e0 + CHUNK_A; if (e1 > NE) e1 = NE;
        for (int j = threadIdx.x; j < NBINS; j += 1024) hist[j] = 0;
        __syncthreads();
        for (int p = e0 + threadIdx.x; p < e1; p += 1024)
            atomicAdd(&hist[ei[NE + p] >> 8], 1);
        __syncthreads();
        for (int j = threadIdx.x; j < NBINS; j += 1024) {
            int c = hist[j];
            rbase[j] = c ? atomicAdd(&bin_cursor[j], c) : 0;
        }
        __syncthreads();
        for (int p = e0 + threadIdx.x; p < e1; p += 1024) {
            int s = ei[p];
            int d = ei[NE + p];
            int bb = d >> 8;
            int pos = atomicAdd(&rbase[bb], 1);
            if (pos < (bb + 1) * BIN_CAP)          // 16-sigma overflow guard
                ebin[pos] = s | ((d & 255) << 17);
        }
        return;
    }

    // ---- gemm1 path: H = bf16(x @ W1), 128x128 tile, 16 waves, dbuf K-loop ----
    float* As = (float*)smem;           // 2 x [128][32] fp32 (buf stride 4096 floats)
    short* Bs = (short*)(smem + 8192);  // 2 x [128][32] bf16 (buf stride 4096 shorts)

    const int tid  = threadIdx.x;
    const int wave = tid >> 6;          // 0..15
    const int lane = tid & 63;
    const int quad = lane >> 4;
    const int l16  = lane & 15;
    const int wy = wave >> 1, wx = wave & 1;
    const int m0 = (bi * 2 + (br == 2 ? 1 : 0)) * 128;

    f32x4 acc[4] = {};

    auto stage = [&](int d, int kk) {
        {
            int row = tid >> 3, cc = tid & 7;
            int gr  = m0 + row; if (gr > NN - 1) gr = NN - 1;
            const float* gp = X + (size_t)gr * NF + kk + cc * 4;
            __builtin_amdgcn_global_load_lds(
                (const __attribute__((address_space(1))) void*)gp,
                (__attribute__((address_space(3))) void*)&As[d * 4096 + wave * 256],
                16, 0, 0);
        }
        if (wave < 8) {
            int n = tid >> 2, cc = tid & 3;
            const __hip_bfloat16* gp = W1t + (size_t)n * NF + kk + cc * 8;
            __builtin_amdgcn_global_load_lds(
                (const __attribute__((address_space(1))) void*)gp,
                (__attribute__((address_space(3))) void*)&Bs[d * 4096 + wave * 512],
                16, 0, 0);
        }
    };

    stage(0, 0);
    __syncthreads();

    int cur = 0;
    #pragma unroll
    for (int k0 = 0; k0 < NF; k0 += 32) {
        if (k0 + 32 < NF) stage(cur ^ 1, k0 + 32);

        bf16x8 a_frag, b_frag[4];
        {
            const float* ap = &As[cur * 4096 + (wy * 16 + l16) * 32 + quad * 8];
            f32x4 a0 = *(const f32x4*)ap;
            f32x4 a1 = *(const f32x4*)(ap + 4);
            bf16x8 af;
            af[0] = bfbits(a0.x); af[1] = bfbits(a0.y);
            af[2] = bfbits(a0.z); af[3] = bfbits(a0.w);
            af[4] = bfbits(a1.x); af[5] = bfbits(a1.y);
            af[6] = bfbits(a1.z); af[7] = bfbits(a1.w);
            a_frag = af;
        }
        #pragma unroll
        for (int ni = 0; ni < 4; ++ni) {
            const short* bp = &Bs[cur * 4096 + (wx * 64 + ni * 16 + l16) * 32 + quad * 8];
            b_frag[ni] = *(const bf16x8*)bp;
        }
        #pragma unroll
        for (int ni = 0; ni < 4; ++ni)
            acc[ni] = __builtin_amdgcn_mfma_f32_16x16x32_bf16(
                a_frag, b_frag[ni], acc[ni], 0, 0, 0);

        __syncthreads();
        cur ^= 1;
    }

    #pragma unroll
    for (int v = 0; v < 4; ++v) {
        int r = m0 + wy * 16 + quad * 4 + v;
        if (r < NN) {
            #pragma unroll
            for (int ni = 0; ni < 4; ++ni) {
                int c = wx * 64 + ni * 16 + l16;
                H[(size_t)r * NH + c] = __float2bfloat16(acc[ni][v]);
            }
        }
    }
}

// ---------------- K2: per-bin count + scan + offr/dinv + counting sort (replaces count/scan/passB) ----------------
__global__ __launch_bounds__(512) void buildK2(const int* __restrict__ ebin,
                                               const int* __restrict__ bin_cursor,
                                               int2* __restrict__ offr,
                                               float* __restrict__ dinv,
                                               int* __restrict__ erec4) {
    __shared__ int ecache[BIN_CAP];   // 20 KB
    __shared__ int hist[256];
    __shared__ int scn[256];
    __shared__ int wsum4[4];

    const int b   = blockIdx.x;
    const int tid = threadIdx.x;
    const int n0  = b << 8;
    const int nodes = (NN - n0 > 256) ? 256 : (NN - n0);
    const int base = b * BIN_CAP;
    int cnt = bin_cursor[b] - base;
    if (cnt > BIN_CAP) cnt = BIN_CAP;

    for (int j = tid; j < 256; j += 512) hist[j] = 0;
    __syncthreads();

    // pass 1: cache segment in LDS + per-node histogram
    for (int p = tid; p < cnt; p += 512) {
        int e = ebin[base + p];
        ecache[p] = e;
        atomicAdd(&hist[e >> 17], 1);
    }
    __syncthreads();

    // 256-wide exclusive scan (4 waves)
    int v = 0, s = 0;
    const int lane = tid & 63, wave = tid >> 6;
    if (tid < 256) {
        v = hist[tid];
        s = v;
        #pragma unroll
        for (int off = 1; off < 64; off <<= 1) {
            int u = __shfl_up(s, off, 64);
            if (lane >= off) s += u;
        }
        if (lane == 63) wsum4[wave] = s;
    }
    __syncthreads();
    if (tid == 0) {
        int a = 0;
        #pragma unroll
        for (int w = 0; w < 4; ++w) { int t = wsum4[w]; wsum4[w] = a; a += t; }
    }
    __syncthreads();
    if (tid < 256) {
        int excl = (s - v) + wsum4[wave];
        scn[tid] = excl;
        if (tid < nodes) {
            offr[n0 + tid] = make_int2(base + excl, base + excl + v);
            dinv[n0 + tid] = rsqrtf((float)v + 1.0f);   // +1 self loop
        }
    }
    __syncthreads();

    // pass 2: counting sort from LDS -> erec4 (src only; weight factorized into aggs)
    for (int p = tid; p < cnt; p += 512) {
        int e = ecache[p];
        int dl = e >> 17;
        int pos = atomicAdd(&scn[dl], 1);
        if (pos < BIN_CAP) erec4[base + pos] = e & 0x1FFFF;
    }
}

// ---------------- FUSED: layer-1 gather (group-per-node) + layer-2 GEMM from LDS ----------------
// 1024 threads/block: 64 gather groups x 2 nodes; MFMA phase waves 0..7.
// Weight = dinv[src] in-loop; dinv[dst] factored out of the edge sum (linearity).
__global__ __launch_bounds__(1024, 2) void agg1_gemm2(
        const int2* __restrict__ offr, const int* __restrict__ erec4,
        const float* __restrict__ dinv, const __hip_bfloat16* __restrict__ H,
        const float* __restrict__ b1, const __hip_bfloat16* __restrict__ W2t,
        __hip_bfloat16* __restrict__ H2p) {
    __shared__ __align__(16) short As[128 * 128];   // 32 KB swizzled Hagg tile
    const int tid  = threadIdx.x;
    const int wave = tid >> 6;      // 0..15
    const int lane = tid & 63;
    const int quad = lane >> 4;
    const int l16  = lane & 15;
    const int grp  = tid >> 4;      // 0..63 gather group
    const int m0   = blockIdx.x * 128;
    const char* Hb = (const char*)H;
    const unsigned lb = (unsigned)(l16 << 4);

    #pragma unroll 1
    for (int rd = 0; rd < 2; ++rd) {
        int nl = rd * 64 + grp;
        int node = m0 + nl;
        if (node < NN) {
            int2 be = offr[node];
            int beg = be.x, end = be.y;
            float dls = dinv[node];
            float ac[8] = {};
            for (int p = beg; p < end; p += 4) {
                int s0 = erec4[p];
                int s1 = (p + 1 < end) ? erec4[p + 1] : 0;
                int s2 = (p + 2 < end) ? erec4[p + 2] : 0;
                int s3 = (p + 3 < end) ? erec4[p + 3] : 0;
                float w0 = dinv[s0];
                float w1 = (p + 1 < end) ? dinv[s1] : 0.f;
                float w2 = (p + 2 < end) ? dinv[s2] : 0.f;
                float w3 = (p + 3 < end) ? dinv[s3] : 0.f;
                uint4 h0 = *(const uint4*)(Hb + (((unsigned)s0) << 8) + lb);
                uint4 h1 = *(const uint4*)(Hb + (((unsigned)s1) << 8) + lb);
                uint4 h2 = *(const uint4*)(Hb + (((unsigned)s2) << 8) + lb);
                uint4 h3 = *(const uint4*)(Hb + (((unsigned)s3) << 8) + lb);
                #define ACC8(hv, ww) { \
                    float2 q0 = cvt2(hv.x), q1 = cvt2(hv.y), q2 = cvt2(hv.z), q3 = cvt2(hv.w); \
                    ac[0] += q0.x * (ww); ac[1] += q0.y * (ww); \
                    ac[2] += q1.x * (ww); ac[3] += q1.y * (ww); \
                    ac[4] += q2.x * (ww); ac[5] += q2.y * (ww); \
                    ac[6] += q3.x * (ww); ac[7] += q3.y * (ww); }
                ACC8(h0, w0) ACC8(h1, w1) ACC8(h2, w2) ACC8(h3, w3)
                #undef ACC8
            }
            // scale by dinv[dst], add self loop + bias, relu -> bf16 row in LDS
            float sl = dls * dls;
            uint4 hs = *(const uint4*)(Hb + (((unsigned)node) << 8) + lb);
            float2 s0f = cvt2(hs.x), s1f = cvt2(hs.y), s2f = cvt2(hs.z), s3f = cvt2(hs.w);
            const float4* bb = reinterpret_cast<const float4*>(b1 + l16 * 8);
            float4 ba = bb[0], bc = bb[1];
            float o0 = fmaxf(ac[0] * dls + s0f.x * sl + ba.x, 0.f);
            float o1 = fmaxf(ac[1] * dls + s0f.y * sl + ba.y, 0.f);
            float o2 = fmaxf(ac[2] * dls + s1f.x * sl + ba.z, 0.f);
            float o3 = fmaxf(ac[3] * dls + s1f.y * sl + ba.w, 0.f);
            float o4 = fmaxf(ac[4] * dls + s2f.x * sl + bc.x, 0.f);
            float o5 = fmaxf(ac[5] * dls + s2f.y * sl + bc.y, 0.f);
            float o6 = fmaxf(ac[6] * dls + s3f.x * sl + bc.z, 0.f);
            float o7 = fmaxf(ac[7] * dls + s3f.y * sl + bc.w, 0.f);
            uint4 ov;
            ov.x = pk2(o0, o1);
            ov.y = pk2(o2, o3);
            ov.z = pk2(o4, o5);
            ov.w = pk2(o6, o7);
            unsigned cb = lb ^ (((unsigned)nl & 7u) << 4);   // XOR-swizzle (G4)
            *reinterpret_cast<uint4*>((char*)As + nl * 256 + cb) = ov;
        }
    }

    // ---- W2 fragments to registers (16KB, L2-hot; only MFMA waves need them) ----
    bf16x8 bfr[4][3];
    if (wave < 8) {
        #pragma unroll
        for (int ks = 0; ks < 4; ++ks)
            #pragma unroll
            for (int ni = 0; ni < 3; ++ni)
                bfr[ks][ni] = *(const bf16x8*)(W2t + (size_t)(ni * 16 + l16) * NH + ks * 32 + quad * 8);
    }

    __syncthreads();
    if (wave >= 8) return;

    // ---- phase 2: 128x48x128 MFMA from LDS, waves 0..7 x 16 rows ----
    f32x4 acc2[3] = {};
    #pragma unroll
    for (int ks = 0; ks < 4; ++ks) {
        int row = wave * 16 + l16;
        unsigned cb = ((unsigned)(ks * 64 + quad * 16)) ^ (((unsigned)row & 7u) << 4);
        bf16x8 afr = *(const bf16x8*)((const char*)As + row * 256 + cb);
        #pragma unroll
        for (int ni = 0; ni < 3; ++ni)
            acc2[ni] = __builtin_amdgcn_mfma_f32_16x16x32_bf16(
                afr, bfr[ks][ni], acc2[ni], 0, 0, 0);
    }

    #pragma unroll
    for (int v = 0; v < 4; ++v) {
        int r = m0 + wave * 16 + quad * 4 + v;
        if (r < NN) {
            #pragma unroll
            for (int ni = 0; ni < 3; ++ni) {
                int c = ni * 16 + l16;
                H2p[(size_t)r * NC2 + c] = __float2bfloat16(acc2[ni][v]);
            }
        }
    }
}

// ---------------- layer-2 gather (16 lanes per node) + self + bias + log_softmax ----------------
__global__ void agg2_lsm(const int2* __restrict__ offr, const int* __restrict__ erec4,
                         const float* __restrict__ dinv, const __hip_bfloat16* __restrict__ H2p,
                         const float* __restrict__ b2, float* __restrict__ out) {
    int node = (blockIdx.x * blockDim.x + threadIdx.x) >> 4;
    if (node >= NN) return;
    int l16 = threadIdx.x & 15;
    const char* Hb = (const char*)H2p;
    const bool lv = (l16 < 12);      // 12 lanes x 8B = 96B = 48 bf16 row
    const unsigned lo = (unsigned)(l16 * 8);
    const uint2 zz = make_uint2(0u, 0u);
    float a0 = 0.f, a1 = 0.f, a2 = 0.f, a3 = 0.f;
    int2 be = offr[node];
    int beg = be.x, end = be.y;
    float di = dinv[node];
    for (int p = beg; p < end; p += 4) {
        int s0 = erec4[p];
        int s1 = (p + 1 < end) ? erec4[p + 1] : 0;
        int s2 = (p + 2 < end) ? erec4[p + 2] : 0;
        int s3 = (p + 3 < end) ? erec4[p + 3] : 0;
        float w0 = dinv[s0];
        float w1 = (p + 1 < end) ? dinv[s1] : 0.f;
        float w2 = (p + 2 < end) ? dinv[s2] : 0.f;
        float w3 = (p + 3 < end) ? dinv[s3] : 0.f;
        uint2 h0 = lv ? *(const uint2*)(Hb + (unsigned)s0 * 96u + lo) : zz;
        uint2 h1 = lv ? *(const uint2*)(Hb + (unsigned)s1 * 96u + lo) : zz;
        uint2 h2 = lv ? *(const uint2*)(Hb + (unsigned)s2 * 96u + lo) : zz;
        uint2 h3 = lv ? *(const uint2*)(Hb + (unsigned)s3 * 96u + lo) : zz;
        #define ACC4(hv, ww) { \
            float2 q0 = cvt2(hv.x), q1 = cvt2(hv.y); \
            a0 += q0.x * (ww); a1 += q0.y * (ww); \
            a2 += q1.x * (ww); a3 += q1.y * (ww); }
        ACC4(h0, w0) ACC4(h1, w1) ACC4(h2, w2) ACC4(h3, w3)
        #undef ACC4
    }
    float v0, v1, v2, v3;
    bool valid = (l16 < 10);   // classes l16*4..l16*4+3 < 40
    if (valid) {
        float sl = di * di;
        uint2 hs = *(const uint2*)(Hb + (unsigned)node * 96u + lo);
        float2 s0f = cvt2(hs.x), s1f = cvt2(hs.y);
        float4 bb = *reinterpret_cast<const float4*>(b2 + l16 * 4);
        v0 = a0 * di + s0f.x * sl + bb.x;
        v1 = a1 * di + s0f.y * sl + bb.y;
        v2 = a2 * di + s1f.x * sl + bb.z;
        v3 = a3 * di + s1f.y * sl + bb.w;
    } else {
        v0 = v1 = v2 = v3 = -INFINITY;
    }
    float m = fmaxf(fmaxf(v0, v1), fmaxf(v2, v3));
    #pragma unroll
    for (int off = 8; off; off >>= 1) m = fmaxf(m, __shfl_xor(m, off, 64));
    float ex = expf(v0 - m) + expf(v1 - m) + expf(v2 - m) + expf(v3 - m);
    #pragma unroll
    for (int off = 8; off; off >>= 1) ex += __shfl_xor(ex, off, 64);
    float ls = logf(ex);
    if (valid) {
        float4 o;
        o.x = v0 - m - ls; o.y = v1 - m - ls;
        o.z = v2 - m - ls; o.w = v3 - m - ls;
        *reinterpret_cast<float4*>(out + (size_t)node * NC + l16 * 4) = o;
    }
}

extern "C" void kernel_launch(void* const* d_in, const int* in_sizes, int n_in,
                              void* d_out, int out_size, void* d_ws, size_t ws_size,
                              hipStream_t stream) {
    const float* x  = (const float*)d_in[0];
    const int*   ei = (const int*)d_in[1];
    const float* W1 = (const float*)d_in[2];
    const float* b1 = (const float*)d_in[3];
    const float* W2 = (const float*)d_in[4];
    const float* b2 = (const float*)d_in[5];
    float* out = (float*)d_out;

    int* wsb = (int*)d_ws;
    int2*  offr       = (int2*)wsb;
    int*   bin_cursor = wsb + OFF_CURSOR;
    float* dinv       = (float*)(wsb + OFF_DINV);
    __hip_bfloat16* H   = (__hip_bfloat16*)(wsb + OFF_H);
    __hip_bfloat16* W1t = (__hip_bfloat16*)(wsb + OFF_W1T);
    __hip_bfloat16* W2t = (__hip_bfloat16*)(wsb + OFF_W2T);
    int* ebin  = wsb + OFF_EBIN;
    int* erec4 = wsb + OFF_EREC4;
    __hip_bfloat16* H2p = (__hip_bfloat16*)(wsb + OFF_H2P);

    // K0: cursor bases + weight transposes (no memset, no count pass, no scans)
    initk<<<(NH * NF + 255) / 256, 256, 0, stream>>>(bin_cursor, W1, W1t, W2, W2t);

    // K1: gemm1 (MFMA, 1024 thr, dbuf) interleaved with pass A binning
    gemm1_passA<<<GEMM1_NB + NB_A, 1024, 0, stream>>>(ei, bin_cursor, ebin, x, W1t, H);

    // K2: per-bin hist + scan + offr/dinv + counting sort -> erec4 (4B/edge)
    buildK2<<<NBINS, 512, 0, stream>>>(ebin, bin_cursor, offr, dinv, erec4);

    // K3: FUSED layer-1 gather + layer-2 GEMM -> H2p
    agg1_gemm2<<<(NN + 127) / 128, 1024, 0, stream>>>(offr, erec4, dinv, H, b1, W2t, H2p);

    // K4: layer-2 gather + self + bias + log_softmax -> out
    {
        long long threads = (long long)NN * 16;
        agg2_lsm<<<(unsigned)((threads + 255) / 256), 256, 0, stream>>>(
            offr, erec4, dinv, H2p, b2, out);
    }
}

// Round 6
// 315.426 us; speedup vs baseline: 1.3427x; 1.0183x over previous
//
#include <hip/hip_runtime.h>
#include <hip/hip_bf16.h>
#include <math.h>

#define NN 100000      // nodes
#define NE 1600000     // edges
#define NF 256         // input features
#define NH 128         // hidden
#define NC 40          // classes
#define NCP 64         // padded classes for W2t (rows >=40 zero)
#define NC2 48         // packed H2p row width (classes 40..47 are zero)

#define NBINS     ((NN + 255) / 256)    // 391
#define BIN_CAP   5120                  // mean bin load 4096, sd~64 -> 16-sigma safe
#define CHUNK_A   4096
#define NB_A      ((NE + CHUNK_A - 1) / CHUNK_A)       // 391
#define GEMM1_NB  ((NN + 127) / 128)    // 782

// Workspace layout (4-byte units), max usage ~22.9M units (91.6MB):
//   offr       [0,       200000)   int2 per node {beg,end} into erec4
//   bin_cursor [200128,  200519)
//   dinv       [300160,  400160)
//   H          [3600192, 10000192) (bf16 NN*NH)
//   w1t        [10000192,10016576) (bf16 [128][256])
//   w2t        [10016576,10020672) (bf16 [64][128], rows >=40 zero)
//   ebin       [16400192,18402112) (NBINS*BIN_CAP ints, dead after buildK2)
//   erec4      [18402112,20404032) (NBINS*BIN_CAP ints: src per edge)
//   H2p        [20404032,22804032) (bf16 [NN][48])
#define OFF_CURSOR  200128
#define OFF_DINV    300160
#define OFF_H       3600192
#define OFF_W1T     10000192
#define OFF_W2T     10016576
#define OFF_EBIN    16400192
#define OFF_EREC4   18402112
#define OFF_H2P     20404032

using f32x4  = __attribute__((ext_vector_type(4))) float;
using bf16x8 = __attribute__((ext_vector_type(8))) short;

// decode packed pair of bf16 (lo, hi) to fp32x2 — exact, pure bit ops
__device__ inline float2 cvt2(unsigned u) {
    float2 f;
    f.x = __uint_as_float(u << 16);
    f.y = __uint_as_float(u & 0xffff0000u);
    return f;
}

__device__ inline short bfbits(float f) {
    __hip_bfloat16 h = __float2bfloat16(f);
    return *reinterpret_cast<short*>(&h);
}

__device__ inline unsigned pk2(float lo, float hi) {
    return (unsigned)(unsigned short)bfbits(lo) | ((unsigned)(unsigned short)bfbits(hi) << 16);
}

// ---------------- K0: bin cursor bases + W1t/W2t prep ----------------
__global__ void initk(int* __restrict__ bin_cursor,
                      const float* __restrict__ W1, __hip_bfloat16* __restrict__ W1t,
                      const float* __restrict__ W2, __hip_bfloat16* __restrict__ W2t) {
    int t = blockIdx.x * blockDim.x + threadIdx.x;
    if (t < NBINS) bin_cursor[t] = t * BIN_CAP;
    if (t < NH * NF) {
        int n = t >> 8;
        int k = t & (NF - 1);
        W1t[t] = __float2bfloat16(W1[(size_t)k * NH + n]);
    }
    if (t < NCP * NH) {
        int n = t >> 7;
        int k = t & (NH - 1);
        W2t[t] = __float2bfloat16((n < NC) ? W2[(size_t)k * NC + n] : 0.f);
    }
}

// ---------------- K1: FUSED layer-1 MFMA GEMM (1024 thr, reg-staged bf16 As) + pass A ----------------
// Block pattern (3k blocks): b%3==1 -> passA chunk b/3; else gemm tile 2*(b/3)+(b%3==2)
// As reg-staged: X fp32 -> regs -> bf16 -> LDS. Convert is off the MFMA critical path
// (issued pre-MFMA, committed post-MFMA; HBM latency hides under MFMA). LDS 32KB.
__global__ __launch_bounds__(1024, 2) void gemm1_passA(
        const int* __restrict__ ei, int* __restrict__ bin_cursor,
        int* __restrict__ ebin,
        const float* __restrict__ X, const __hip_bfloat16* __restrict__ W1t,
        __hip_bfloat16* __restrict__ H) {
    __shared__ __align__(16) int smem[8192];   // 32 KB: As dbuf bf16(16K)+Bs dbuf(16K) OR passA hist/rbase

    const int bi = blockIdx.x / 3;
    const int br = blockIdx.x % 3;

    if (br == 1) {
        // ---- pass A: partition 4096 edges into 256-node bins, run-coalesced writes ----
        int* hist  = smem;
        int* rbase = smem + NBINS;
        int e0 = bi * CHUNK_A;
        int e1 = e0 + CHUNK_A; if (e1 > NE) e1 = NE;
        for (int j = threadIdx.x; j < NBINS; j += 1024) hist[j] = 0;
        __syncthreads();
        for (int p = e0 + threadIdx.x; p < e1; p += 1024)
            atomicAdd(&hist[ei[NE + p] >> 8], 1);
        __syncthreads();
        for (int j = threadIdx.x; j < NBINS; j += 1024) {
            int c = hist[j];
            rbase[j] = c ? atomicAdd(&bin_cursor[j], c) : 0;
        }
        __syncthreads();
        for (int p = e0 + threadIdx.x; p < e1; p += 1024) {
            int s = ei[p];
            int d = ei[NE + p];
            int bb = d >> 8;
            int pos = atomicAdd(&rbase[bb], 1);
            if (pos < (bb + 1) * BIN_CAP)          // 16-sigma overflow guard
                ebin[pos] = s | ((d & 255) << 17);
        }
        return;
    }

    // ---- gemm1 path: H = bf16(x @ W1), 128x128 tile, 16 waves, dbuf K-loop ----
    short* As = (short*)smem;            // 2 x [128][32] bf16 (4096 shorts per buffer)
    short* Bs = (short*)smem + 8192;     // 2 x [128][32] bf16

    const int tid  = threadIdx.x;
    const int wave = tid >> 6;          // 0..15
    const int lane = tid & 63;
    const int quad = lane >> 4;
    const int l16  = lane & 15;
    const int wy = wave >> 1, wx = wave & 1;
    const int m0 = (bi * 2 + (br == 2 ? 1 : 0)) * 128;

    // per-thread X staging address: 1 chunk of 4 fp32 per K-step
    const int xrow = tid >> 3, xc4 = tid & 7;
    int gr = m0 + xrow; if (gr > NN - 1) gr = NN - 1;
    const float* xbase = X + (size_t)gr * NF + xc4 * 4;
    const int xdst = xrow * 32 + xc4 * 4;   // short offset within As buffer

    f32x4 acc[4] = {};

    auto stageB = [&](int d, int kk) {
        if (wave < 8) {
            int n = tid >> 2, cc = tid & 3;
            const __hip_bfloat16* gp = W1t + (size_t)n * NF + kk + cc * 8;
            __builtin_amdgcn_global_load_lds(
                (const __attribute__((address_space(1))) void*)gp,
                (__attribute__((address_space(3))) void*)&Bs[d * 4096 + wave * 512],
                16, 0, 0);
        }
    };

    // prologue: buffer 0
    {
        f32x4 xr = *(const f32x4*)xbase;
        stageB(0, 0);
        uint2 wpk;
        wpk.x = pk2(xr.x, xr.y);
        wpk.y = pk2(xr.z, xr.w);
        *reinterpret_cast<uint2*>(&As[xdst]) = wpk;
    }
    __syncthreads();

    int cur = 0;
    #pragma unroll
    for (int k0 = 0; k0 < NF; k0 += 32) {
        const bool more = (k0 + 32 < NF);
        f32x4 xn;
        if (more) {
            xn = *(const f32x4*)(xbase + k0 + 32);   // issue early: latency hides under MFMA
            stageB(cur ^ 1, k0 + 32);
        }

        bf16x8 a_frag = *(const bf16x8*)&As[cur * 4096 + (wy * 16 + l16) * 32 + quad * 8];
        bf16x8 b_frag[4];
        #pragma unroll
        for (int ni = 0; ni < 4; ++ni)
            b_frag[ni] = *(const bf16x8*)&Bs[cur * 4096 + (wx * 64 + ni * 16 + l16) * 32 + quad * 8];
        #pragma unroll
        for (int ni = 0; ni < 4; ++ni)
            acc[ni] = __builtin_amdgcn_mfma_f32_16x16x32_bf16(
                a_frag, b_frag[ni], acc[ni], 0, 0, 0);

        if (more) {
            uint2 wpk;
            wpk.x = pk2(xn.x, xn.y);
            wpk.y = pk2(xn.z, xn.w);
            *reinterpret_cast<uint2*>(&As[(cur ^ 1) * 4096 + xdst]) = wpk;
        }
        __syncthreads();   // drains Bs gload_lds (vmcnt 0) + orders As ds_write for next iter
        cur ^= 1;
    }

    #pragma unroll
    for (int v = 0; v < 4; ++v) {
        int r = m0 + wy * 16 + quad * 4 + v;
        if (r < NN) {
            #pragma unroll
            for (int ni = 0; ni < 4; ++ni) {
                int c = wx * 64 + ni * 16 + l16;
                H[(size_t)r * NH + c] = __float2bfloat16(acc[ni][v]);
            }
        }
    }
}

// ---------------- K2: per-bin count + scan + offr/dinv + counting sort ----------------
__global__ __launch_bounds__(512) void buildK2(const int* __restrict__ ebin,
                                               const int* __restrict__ bin_cursor,
                                               int2* __restrict__ offr,
                                               float* __restrict__ dinv,
                                               int* __restrict__ erec4) {
    __shared__ int ecache[BIN_CAP];   // 20 KB
    __shared__ int hist[256];
    __shared__ int scn[256];
    __shared__ int wsum4[4];

    const int b   = blockIdx.x;
    const int tid = threadIdx.x;
    const int n0  = b << 8;
    const int nodes = (NN - n0 > 256) ? 256 : (NN - n0);
    const int base = b * BIN_CAP;
    int cnt = bin_cursor[b] - base;
    if (cnt > BIN_CAP) cnt = BIN_CAP;

    for (int j = tid; j < 256; j += 512) hist[j] = 0;
    __syncthreads();

    // pass 1: cache segment in LDS + per-node histogram
    for (int p = tid; p < cnt; p += 512) {
        int e = ebin[base + p];
        ecache[p] = e;
        atomicAdd(&hist[e >> 17], 1);
    }
    __syncthreads();

    // 256-wide exclusive scan (4 waves)
    int v = 0, s = 0;
    const int lane = tid & 63, wave = tid >> 6;
    if (tid < 256) {
        v = hist[tid];
        s = v;
        #pragma unroll
        for (int off = 1; off < 64; off <<= 1) {
            int u = __shfl_up(s, off, 64);
            if (lane >= off) s += u;
        }
        if (lane == 63) wsum4[wave] = s;
    }
    __syncthreads();
    if (tid == 0) {
        int a = 0;
        #pragma unroll
        for (int w = 0; w < 4; ++w) { int t = wsum4[w]; wsum4[w] = a; a += t; }
    }
    __syncthreads();
    if (tid < 256) {
        int excl = (s - v) + wsum4[wave];
        scn[tid] = excl;
        if (tid < nodes) {
            offr[n0 + tid] = make_int2(base + excl, base + excl + v);
            dinv[n0 + tid] = rsqrtf((float)v + 1.0f);   // +1 self loop
        }
    }
    __syncthreads();

    // pass 2: counting sort from LDS -> erec4 (src only; weight factorized into aggs)
    for (int p = tid; p < cnt; p += 512) {
        int e = ecache[p];
        int dl = e >> 17;
        int pos = atomicAdd(&scn[dl], 1);
        if (pos < BIN_CAP) erec4[base + pos] = e & 0x1FFFF;
    }
}

// ---------------- FUSED: layer-1 gather (group-per-node) + layer-2 GEMM from LDS ----------------
// 1024 threads/block: 64 gather groups x 2 nodes; MFMA phase waves 0..7.
// Weight = dinv[src] in-loop; dinv[dst] factored out of the edge sum (linearity).
__global__ __launch_bounds__(1024, 2) void agg1_gemm2(
        const int2* __restrict__ offr, const int* __restrict__ erec4,
        const float* __restrict__ dinv, const __hip_bfloat16* __restrict__ H,
        const float* __restrict__ b1, const __hip_bfloat16* __restrict__ W2t,
        __hip_bfloat16* __restrict__ H2p) {
    __shared__ __align__(16) short As[128 * 128];   // 32 KB swizzled Hagg tile
    const int tid  = threadIdx.x;
    const int wave = tid >> 6;      // 0..15
    const int lane = tid & 63;
    const int quad = lane >> 4;
    const int l16  = lane & 15;
    const int grp  = tid >> 4;      // 0..63 gather group
    const int m0   = blockIdx.x * 128;
    const char* Hb = (const char*)H;
    const unsigned lb = (unsigned)(l16 << 4);

    #pragma unroll 1
    for (int rd = 0; rd < 2; ++rd) {
        int nl = rd * 64 + grp;
        int node = m0 + nl;
        if (node < NN) {
            int2 be = offr[node];
            int beg = be.x, end = be.y;
            float dls = dinv[node];
            float ac[8] = {};
            for (int p = beg; p < end; p += 4) {
                int s0 = erec4[p];
                int s1 = (p + 1 < end) ? erec4[p + 1] : 0;
                int s2 = (p + 2 < end) ? erec4[p + 2] : 0;
                int s3 = (p + 3 < end) ? erec4[p + 3] : 0;
                float w0 = dinv[s0];
                float w1 = (p + 1 < end) ? dinv[s1] : 0.f;
                float w2 = (p + 2 < end) ? dinv[s2] : 0.f;
                float w3 = (p + 3 < end) ? dinv[s3] : 0.f;
                uint4 h0 = *(const uint4*)(Hb + (((unsigned)s0) << 8) + lb);
                uint4 h1 = *(const uint4*)(Hb + (((unsigned)s1) << 8) + lb);
                uint4 h2 = *(const uint4*)(Hb + (((unsigned)s2) << 8) + lb);
                uint4 h3 = *(const uint4*)(Hb + (((unsigned)s3) << 8) + lb);
                #define ACC8(hv, ww) { \
                    float2 q0 = cvt2(hv.x), q1 = cvt2(hv.y), q2 = cvt2(hv.z), q3 = cvt2(hv.w); \
                    ac[0] += q0.x * (ww); ac[1] += q0.y * (ww); \
                    ac[2] += q1.x * (ww); ac[3] += q1.y * (ww); \
                    ac[4] += q2.x * (ww); ac[5] += q2.y * (ww); \
                    ac[6] += q3.x * (ww); ac[7] += q3.y * (ww); }
                ACC8(h0, w0) ACC8(h1, w1) ACC8(h2, w2) ACC8(h3, w3)
                #undef ACC8
            }
            // scale by dinv[dst], add self loop + bias, relu -> bf16 row in LDS
            float sl = dls * dls;
            uint4 hs = *(const uint4*)(Hb + (((unsigned)node) << 8) + lb);
            float2 s0f = cvt2(hs.x), s1f = cvt2(hs.y), s2f = cvt2(hs.z), s3f = cvt2(hs.w);
            const float4* bb = reinterpret_cast<const float4*>(b1 + l16 * 8);
            float4 ba = bb[0], bc = bb[1];
            float o0 = fmaxf(ac[0] * dls + s0f.x * sl + ba.x, 0.f);
            float o1 = fmaxf(ac[1] * dls + s0f.y * sl + ba.y, 0.f);
            float o2 = fmaxf(ac[2] * dls + s1f.x * sl + ba.z, 0.f);
            float o3 = fmaxf(ac[3] * dls + s1f.y * sl + ba.w, 0.f);
            float o4 = fmaxf(ac[4] * dls + s2f.x * sl + bc.x, 0.f);
            float o5 = fmaxf(ac[5] * dls + s2f.y * sl + bc.y, 0.f);
            float o6 = fmaxf(ac[6] * dls + s3f.x * sl + bc.z, 0.f);
            float o7 = fmaxf(ac[7] * dls + s3f.y * sl + bc.w, 0.f);
            uint4 ov;
            ov.x = pk2(o0, o1);
            ov.y = pk2(o2, o3);
            ov.z = pk2(o4, o5);
            ov.w = pk2(o6, o7);
            unsigned cb = lb ^ (((unsigned)nl & 7u) << 4);   // XOR-swizzle (G4)
            *reinterpret_cast<uint4*>((char*)As + nl * 256 + cb) = ov;
        }
    }

    // ---- W2 fragments to registers (16KB, L2-hot; only MFMA waves need them) ----
    bf16x8 bfr[4][3];
    if (wave < 8) {
        #pragma unroll
        for (int ks = 0; ks < 4; ++ks)
            #pragma unroll
            for (int ni = 0; ni < 3; ++ni)
                bfr[ks][ni] = *(const bf16x8*)(W2t + (size_t)(ni * 16 + l16) * NH + ks * 32 + quad * 8);
    }

    __syncthreads();
    if (wave >= 8) return;

    // ---- phase 2: 128x48x128 MFMA from LDS, waves 0..7 x 16 rows ----
    f32x4 acc2[3] = {};
    #pragma unroll
    for (int ks = 0; ks < 4; ++ks) {
        int row = wave * 16 + l16;
        unsigned cb = ((unsigned)(ks * 64 + quad * 16)) ^ (((unsigned)row & 7u) << 4);
        bf16x8 afr = *(const bf16x8*)((const char*)As + row * 256 + cb);
        #pragma unroll
        for (int ni = 0; ni < 3; ++ni)
            acc2[ni] = __builtin_amdgcn_mfma_f32_16x16x32_bf16(
                afr, bfr[ks][ni], acc2[ni], 0, 0, 0);
    }

    #pragma unroll
    for (int v = 0; v < 4; ++v) {
        int r = m0 + wave * 16 + quad * 4 + v;
        if (r < NN) {
            #pragma unroll
            for (int ni = 0; ni < 3; ++ni) {
                int c = ni * 16 + l16;
                H2p[(size_t)r * NC2 + c] = __float2bfloat16(acc2[ni][v]);
            }
        }
    }
}

// ---------------- layer-2 gather (16 lanes per node, 8 edges in flight) + log_softmax ----------------
__global__ void agg2_lsm(const int2* __restrict__ offr, const int* __restrict__ erec4,
                         const float* __restrict__ dinv, const __hip_bfloat16* __restrict__ H2p,
                         const float* __restrict__ b2, float* __restrict__ out) {
    int node = (blockIdx.x * blockDim.x + threadIdx.x) >> 4;
    if (node >= NN) return;
    int l16 = threadIdx.x & 15;
    const char* Hb = (const char*)H2p;
    const bool lv = (l16 < 12);      // 12 lanes x 8B = 96B = 48 bf16 row
    const unsigned lo = (unsigned)(l16 * 8);
    const uint2 zz = make_uint2(0u, 0u);
    float a0 = 0.f, a1 = 0.f, a2 = 0.f, a3 = 0.f;
    int2 be = offr[node];
    int beg = be.x, end = be.y;
    float di = dinv[node];
    for (int p = beg; p < end; p += 8) {
        int s[8]; float w[8]; uint2 h[8];
        #pragma unroll
        for (int j = 0; j < 8; ++j) s[j] = (p + j < end) ? erec4[p + j] : 0;
        #pragma unroll
        for (int j = 0; j < 8; ++j) w[j] = (p + j < end) ? dinv[s[j]] : 0.f;
        #pragma unroll
        for (int j = 0; j < 8; ++j) h[j] = lv ? *(const uint2*)(Hb + (unsigned)s[j] * 96u + lo) : zz;
        #pragma unroll
        for (int j = 0; j < 8; ++j) {
            float2 q0 = cvt2(h[j].x), q1 = cvt2(h[j].y);
            a0 += q0.x * w[j]; a1 += q0.y * w[j];
            a2 += q1.x * w[j]; a3 += q1.y * w[j];
        }
    }
    float v0, v1, v2, v3;
    bool valid = (l16 < 10);   // classes l16*4..l16*4+3 < 40
    if (valid) {
        float sl = di * di;
        uint2 hs = *(const uint2*)(Hb + (unsigned)node * 96u + lo);
        float2 s0f = cvt2(hs.x), s1f = cvt2(hs.y);
        float4 bb = *reinterpret_cast<const float4*>(b2 + l16 * 4);
        v0 = a0 * di + s0f.x * sl + bb.x;
        v1 = a1 * di + s0f.y * sl + bb.y;
        v2 = a2 * di + s1f.x * sl + bb.z;
        v3 = a3 * di + s1f.y * sl + bb.w;
    } else {
        v0 = v1 = v2 = v3 = -INFINITY;
    }
    float m = fmaxf(fmaxf(v0, v1), fmaxf(v2, v3));
    #pragma unroll
    for (int off = 8; off; off >>= 1) m = fmaxf(m, __shfl_xor(m, off, 64));
    float ex = expf(v0 - m) + expf(v1 - m) + expf(v2 - m) + expf(v3 - m);
    #pragma unroll
    for (int off = 8; off; off >>= 1) ex += __shfl_xor(ex, off, 64);
    float ls = logf(ex);
    if (valid) {
        float4 o;
        o.x = v0 - m - ls; o.y = v1 - m - ls;
        o.z = v2 - m - ls; o.w = v3 - m - ls;
        *reinterpret_cast<float4*>(out + (size_t)node * NC + l16 * 4) = o;
    }
}

extern "C" void kernel_launch(void* const* d_in, const int* in_sizes, int n_in,
                              void* d_out, int out_size, void* d_ws, size_t ws_size,
                              hipStream_t stream) {
    const float* x  = (const float*)d_in[0];
    const int*   ei = (const int*)d_in[1];
    const float* W1 = (const float*)d_in[2];
    const float* b1 = (const float*)d_in[3];
    const float* W2 = (const float*)d_in[4];
    const float* b2 = (const float*)d_in[5];
    float* out = (float*)d_out;

    int* wsb = (int*)d_ws;
    int2*  offr       = (int2*)wsb;
    int*   bin_cursor = wsb + OFF_CURSOR;
    float* dinv       = (float*)(wsb + OFF_DINV);
    __hip_bfloat16* H   = (__hip_bfloat16*)(wsb + OFF_H);
    __hip_bfloat16* W1t = (__hip_bfloat16*)(wsb + OFF_W1T);
    __hip_bfloat16* W2t = (__hip_bfloat16*)(wsb + OFF_W2T);
    int* ebin  = wsb + OFF_EBIN;
    int* erec4 = wsb + OFF_EREC4;
    __hip_bfloat16* H2p = (__hip_bfloat16*)(wsb + OFF_H2P);

    // K0: cursor bases + weight transposes
    initk<<<(NH * NF + 255) / 256, 256, 0, stream>>>(bin_cursor, W1, W1t, W2, W2t);

    // K1: gemm1 (MFMA, reg-staged bf16 As, 1024 thr) interleaved with pass A binning
    gemm1_passA<<<GEMM1_NB + NB_A, 1024, 0, stream>>>(ei, bin_cursor, ebin, x, W1t, H);

    // K2: per-bin hist + scan + offr/dinv + counting sort -> erec4 (4B/edge)
    buildK2<<<NBINS, 512, 0, stream>>>(ebin, bin_cursor, offr, dinv, erec4);

    // K3: FUSED layer-1 gather + layer-2 GEMM -> H2p
    agg1_gemm2<<<(NN + 127) / 128, 1024, 0, stream>>>(offr, erec4, dinv, H, b1, W2t, H2p);

    // K4: layer-2 gather + self + bias + log_softmax -> out
    {
        long long threads = (long long)NN * 16;
        agg2_lsm<<<(unsigned)((threads + 255) / 256), 256, 0, stream>>>(
            offr, erec4, dinv, H2p, b2, out);
    }
}